// Round 1
// baseline (843.933 us; speedup 1.0000x reference)
//
#include <hip/hip_runtime.h>
#include <math.h>

#define NN 100000
#define NE 1600000
#define D 64

// ---------------- degree + counts init ----------------
__global__ void k_init(float* __restrict__ deg, int* __restrict__ counts, int n) {
    int i = blockIdx.x * blockDim.x + threadIdx.x;
    if (i < n) { deg[i] = 1.0f; counts[i] = 0; }   // self-loop weight 1
}

__global__ void k_deg_count(const int* __restrict__ dst, const float* __restrict__ w,
                            float* __restrict__ deg, int* __restrict__ counts, int E) {
    int e = blockIdx.x * blockDim.x + threadIdx.x;
    if (e < E) {
        int d = dst[e];
        atomicAdd(&deg[d], w[e]);
        atomicAdd(&counts[d], 1);
    }
}

__global__ void k_dinv(const float* __restrict__ deg, float* __restrict__ dinv, int n) {
    int i = blockIdx.x * blockDim.x + threadIdx.x;
    if (i < n) {
        float dg = deg[i];
        dinv[i] = (dg > 0.0f) ? rsqrtf(dg) : 0.0f;
    }
}

// ---------------- exclusive scan over counts -> row_ptr ----------------
#define SCAN_B 1024
__global__ void k_scan1(const int* __restrict__ counts, int* __restrict__ row_ptr,
                        int* __restrict__ partials, int n) {
    __shared__ int sm[SCAN_B];
    int t = threadIdx.x;
    int i = blockIdx.x * SCAN_B + t;
    int v = (i < n) ? counts[i] : 0;
    sm[t] = v;
    __syncthreads();
    for (int off = 1; off < SCAN_B; off <<= 1) {
        int add = (t >= off) ? sm[t - off] : 0;
        __syncthreads();
        sm[t] += add;
        __syncthreads();
    }
    if (i < n) row_ptr[i] = sm[t] - v;          // exclusive within block
    if (t == SCAN_B - 1) partials[blockIdx.x] = sm[t];  // block total
}

__global__ void k_scan2(int* __restrict__ partials, int nb) {
    if (threadIdx.x == 0 && blockIdx.x == 0) {
        int run = 0;
        for (int b = 0; b < nb; b++) { int t = partials[b]; partials[b] = run; run += t; }
    }
}

__global__ void k_scan3(int* __restrict__ row_ptr, const int* __restrict__ partials,
                        int* __restrict__ cursor, int n, int E) {
    int i = blockIdx.x * blockDim.x + threadIdx.x;
    if (i < n) {
        int v = row_ptr[i] + partials[i / SCAN_B];
        row_ptr[i] = v;
        cursor[i] = v;
    }
    if (i == 0) row_ptr[n] = E;
}

// ---------------- CSR scatter (fused norm computation) ----------------
__global__ void k_scatter(const int* __restrict__ src, const int* __restrict__ dst,
                          const float* __restrict__ w, const float* __restrict__ dinv,
                          int* __restrict__ cursor, int* __restrict__ col,
                          float* __restrict__ val, int E) {
    int e = blockIdx.x * blockDim.x + threadIdx.x;
    if (e < E) {
        int s = src[e], d = dst[e];
        int p = atomicAdd(&cursor[d], 1);
        col[p] = s;
        val[p] = dinv[s] * w[e] * dinv[d];
    }
}

// ---------------- dense: T = X @ W  (per-wave row, W staged in LDS) ----------------
__global__ void k_gemm(const float* __restrict__ X, const float* __restrict__ W,
                       float* __restrict__ T, int n) {
    __shared__ float Ws[D * D];
    for (int i = threadIdx.x; i < D * D; i += blockDim.x) Ws[i] = W[i];
    __syncthreads();
    int wave = (int)((blockIdx.x * blockDim.x + threadIdx.x) >> 6);
    int lane = threadIdx.x & 63;
    if (wave >= n) return;
    float xv = X[(size_t)wave * D + lane];
    float acc = 0.0f;
#pragma unroll
    for (int k = 0; k < D; k++) acc += __shfl(xv, k) * Ws[k * D + lane];
    T[(size_t)wave * D + lane] = acc;
}

// ---------------- aggregation: out = relu(A*T + b) ; optional fused @W3 ----------------
template <int FUSE_W3>
__global__ void k_agg(const float* __restrict__ T, const int* __restrict__ row_ptr,
                      const int* __restrict__ col, const float* __restrict__ val,
                      const float* __restrict__ dinv, const float* __restrict__ bias,
                      const float* __restrict__ W3, float* __restrict__ out, int n) {
    int wave = (int)((blockIdx.x * blockDim.x + threadIdx.x) >> 6);
    int lane = threadIdx.x & 63;
    if (wave >= n) return;
    int beg = row_ptr[wave], end = row_ptr[wave + 1];
    float dv = dinv[wave];
    float acc = dv * dv * T[(size_t)wave * D + lane];   // self-loop term
    // 1-ahead prefetch of (col,val) to overlap with the dependent row gather
    int u = 0; float nv = 0.0f;
    if (beg < end) { u = col[beg]; nv = val[beg]; }
    for (int i = beg; i < end; i++) {
        int un = 0; float nvn = 0.0f;
        if (i + 1 < end) { un = col[i + 1]; nvn = val[i + 1]; }
        acc += nv * T[(size_t)u * D + lane];
        u = un; nv = nvn;
    }
    float h = fmaxf(acc + bias[lane], 0.0f);
    if (FUSE_W3) {
        float p = h * W3[lane];
#pragma unroll
        for (int off = 32; off; off >>= 1) p += __shfl_xor(p, off);
        if (lane == 0) out[wave] = p;
    } else {
        out[(size_t)wave * D + lane] = h;
    }
}

// ---------------- layer 3: scalar aggregation + sigmoid ----------------
__global__ void k_agg3(const float* __restrict__ t3, const int* __restrict__ row_ptr,
                       const int* __restrict__ col, const float* __restrict__ val,
                       const float* __restrict__ dinv, const float* __restrict__ b3,
                       float* __restrict__ out, int n) {
    int v = blockIdx.x * blockDim.x + threadIdx.x;
    if (v >= n) return;
    float dv = dinv[v];
    float acc = dv * dv * t3[v];
    int beg = row_ptr[v], end = row_ptr[v + 1];
    for (int i = beg; i < end; i++) acc += val[i] * t3[col[i]];
    float z = acc + b3[0];
    out[v] = 1.0f / (1.0f + expf(-z));
}

extern "C" void kernel_launch(void* const* d_in, const int* in_sizes, int n_in,
                              void* d_out, int out_size, void* d_ws, size_t ws_size,
                              hipStream_t stream) {
    const float* x  = (const float*)d_in[0];
    const int*   ei = (const int*)d_in[1];
    const float* w  = (const float*)d_in[2];
    const float* W1 = (const float*)d_in[3];
    const float* b1 = (const float*)d_in[4];
    const float* W2 = (const float*)d_in[5];
    const float* b2 = (const float*)d_in[6];
    const float* W3 = (const float*)d_in[7];
    const float* b3 = (const float*)d_in[8];
    float* out = (float*)d_out;

    const int N = NN, E = NE;
    const int* src = ei;
    const int* dst = ei + E;

    // workspace carve (256B aligned)
    char* p = (char*)d_ws;
    auto alloc = [&](size_t bytes) -> char* {
        char* r = p;
        p += (bytes + 255) & ~(size_t)255;
        return r;
    };
    float* deg     = (float*)alloc((size_t)N * 4);
    float* dinv    = (float*)alloc((size_t)N * 4);
    int*   counts  = (int*)alloc((size_t)N * 4);       // reused as scatter cursor
    int*   row_ptr = (int*)alloc((size_t)(N + 1) * 4);
    int*   partials= (int*)alloc(1024 * 4);
    int*   col     = (int*)alloc((size_t)E * 4);
    float* val     = (float*)alloc((size_t)E * 4);
    float* bufA    = (float*)alloc((size_t)N * D * 4);
    float* bufB    = (float*)alloc((size_t)N * D * 4);
    float* t3      = (float*)alloc((size_t)N * 4);

    const int BT = 256;
    int gN  = (N + BT - 1) / BT;
    int gE  = (E + BT - 1) / BT;
    int nb  = (N + SCAN_B - 1) / SCAN_B;
    int gW  = (N * 64 + BT - 1) / BT;   // wave-per-node grids (4 waves/block)

    // --- graph prep ---
    k_init<<<gN, BT, 0, stream>>>(deg, counts, N);
    k_deg_count<<<gE, BT, 0, stream>>>(dst, w, deg, counts, E);
    k_dinv<<<gN, BT, 0, stream>>>(deg, dinv, N);
    k_scan1<<<nb, SCAN_B, 0, stream>>>(counts, row_ptr, partials, N);
    k_scan2<<<1, 64, 0, stream>>>(partials, nb);
    k_scan3<<<gN, BT, 0, stream>>>(row_ptr, partials, counts, N, E);
    k_scatter<<<gE, BT, 0, stream>>>(src, dst, w, dinv, counts, col, val, E);

    // --- layer 1 ---
    k_gemm<<<gW, BT, 0, stream>>>(x, W1, bufA, N);
    k_agg<0><<<gW, BT, 0, stream>>>(bufA, row_ptr, col, val, dinv, b1, nullptr, bufB, N);
    // --- layer 2 (fused h2 @ W3 epilogue -> t3) ---
    k_gemm<<<gW, BT, 0, stream>>>(bufB, W2, bufA, N);
    k_agg<1><<<gW, BT, 0, stream>>>(bufA, row_ptr, col, val, dinv, b2, W3, t3, N);
    // --- layer 3: scalar aggregation + bias + sigmoid ---
    k_agg3<<<gN, BT, 0, stream>>>(t3, row_ptr, col, val, dinv, b3, out, N);
}

// Round 4
// 617.530 us; speedup vs baseline: 1.3666x; 1.3666x over previous
//
#include <hip/hip_runtime.h>
#include <math.h>

#define NN 100000
#define NE 1600000
#define D 64

// ---------------- degree + counts init ----------------
__global__ void k_init(float* __restrict__ deg, int* __restrict__ counts, int n) {
    int i = blockIdx.x * blockDim.x + threadIdx.x;
    if (i < n) { deg[i] = 1.0f; counts[i] = 0; }   // self-loop weight 1
}

__global__ void k_deg_count(const int* __restrict__ dst, const float* __restrict__ w,
                            float* __restrict__ deg, int* __restrict__ counts, int E) {
    int e = blockIdx.x * blockDim.x + threadIdx.x;
    if (e < E) {
        int d = dst[e];
        atomicAdd(&deg[d], w[e]);
        atomicAdd(&counts[d], 1);
    }
}

__global__ void k_dinv(const float* __restrict__ deg, float* __restrict__ dinv, int n) {
    int i = blockIdx.x * blockDim.x + threadIdx.x;
    if (i < n) {
        float dg = deg[i];
        dinv[i] = (dg > 0.0f) ? rsqrtf(dg) : 0.0f;
    }
}

// ---------------- exclusive scan over counts -> row_ptr ----------------
#define SCAN_B 1024
__global__ void k_scan1(const int* __restrict__ counts, int* __restrict__ row_ptr,
                        int* __restrict__ partials, int n) {
    __shared__ int sm[SCAN_B];
    int t = threadIdx.x;
    int i = blockIdx.x * SCAN_B + t;
    int v = (i < n) ? counts[i] : 0;
    sm[t] = v;
    __syncthreads();
    for (int off = 1; off < SCAN_B; off <<= 1) {
        int add = (t >= off) ? sm[t - off] : 0;
        __syncthreads();
        sm[t] += add;
        __syncthreads();
    }
    if (i < n) row_ptr[i] = sm[t] - v;          // exclusive within block
    if (t == SCAN_B - 1) partials[blockIdx.x] = sm[t];  // block total
}

__global__ void k_scan2(int* __restrict__ partials, int nb) {
    if (threadIdx.x == 0 && blockIdx.x == 0) {
        int run = 0;
        for (int b = 0; b < nb; b++) { int t = partials[b]; partials[b] = run; run += t; }
    }
}

__global__ void k_scan3(int* __restrict__ row_ptr, const int* __restrict__ partials,
                        int* __restrict__ cursor, int n, int E) {
    int i = blockIdx.x * blockDim.x + threadIdx.x;
    if (i < n) {
        int v = row_ptr[i] + partials[i / SCAN_B];
        row_ptr[i] = v;
        cursor[i] = v;
    }
    if (i == 0) row_ptr[n] = E;
}

// ---------------- CSR scatter: packed (src, norm) records ----------------
__global__ void k_scatter(const int* __restrict__ src, const int* __restrict__ dst,
                          const float* __restrict__ w, const float* __restrict__ dinv,
                          int* __restrict__ cursor, int2* __restrict__ edges, int E) {
    int e = blockIdx.x * blockDim.x + threadIdx.x;
    if (e < E) {
        int s = src[e], d = dst[e];
        int p = atomicAdd(&cursor[d], 1);
        float nv = dinv[s] * w[e] * dinv[d];
        edges[p] = make_int2(s, __float_as_int(nv));   // single 8B store
    }
}

// ---------------- dense: T = X @ W  (per-wave row, W staged in LDS) ----------------
__global__ void k_gemm(const float* __restrict__ X, const float* __restrict__ W,
                       float* __restrict__ T, int n) {
    __shared__ float Ws[D * D];
    for (int i = threadIdx.x; i < D * D; i += blockDim.x) Ws[i] = W[i];
    __syncthreads();
    int wave = (int)((blockIdx.x * blockDim.x + threadIdx.x) >> 6);
    int lane = threadIdx.x & 63;
    if (wave >= n) return;
    float xv = X[(size_t)wave * D + lane];
    float acc = 0.0f;
#pragma unroll
    for (int k = 0; k < D; k++) acc += __shfl(xv, k) * Ws[k * D + lane];
    T[(size_t)wave * D + lane] = acc;
}

// ---------------- aggregation: out = relu(A*T + b) ; optional fused @W3 ----------------
// 8-way edge ILP: 8 independent 256B row gathers in flight per wave.
template <int FUSE_W3>
__global__ void k_agg(const float* __restrict__ T, const int* __restrict__ row_ptr,
                      const int2* __restrict__ edges, const float* __restrict__ dinv,
                      const float* __restrict__ bias, const float* __restrict__ W3,
                      float* __restrict__ out, int n) {
    int wave = (int)((blockIdx.x * blockDim.x + threadIdx.x) >> 6);
    int lane = threadIdx.x & 63;
    if (wave >= n) return;
    int beg = row_ptr[wave], end = row_ptr[wave + 1];
    float dv = dinv[wave];
    float acc0 = dv * dv * T[(size_t)wave * D + lane];   // self-loop term
    float acc1 = 0.0f;
    int i = beg;
    for (; i + 8 <= end; i += 8) {
        int2 e0 = edges[i + 0], e1 = edges[i + 1], e2 = edges[i + 2], e3 = edges[i + 3];
        int2 e4 = edges[i + 4], e5 = edges[i + 5], e6 = edges[i + 6], e7 = edges[i + 7];
        float a0 = T[(size_t)e0.x * D + lane];
        float a1 = T[(size_t)e1.x * D + lane];
        float a2 = T[(size_t)e2.x * D + lane];
        float a3 = T[(size_t)e3.x * D + lane];
        float a4 = T[(size_t)e4.x * D + lane];
        float a5 = T[(size_t)e5.x * D + lane];
        float a6 = T[(size_t)e6.x * D + lane];
        float a7 = T[(size_t)e7.x * D + lane];
        acc0 += __int_as_float(e0.y) * a0; acc1 += __int_as_float(e1.y) * a1;
        acc0 += __int_as_float(e2.y) * a2; acc1 += __int_as_float(e3.y) * a3;
        acc0 += __int_as_float(e4.y) * a4; acc1 += __int_as_float(e5.y) * a5;
        acc0 += __int_as_float(e6.y) * a6; acc1 += __int_as_float(e7.y) * a7;
    }
    for (; i + 4 <= end; i += 4) {
        int2 e0 = edges[i + 0], e1 = edges[i + 1], e2 = edges[i + 2], e3 = edges[i + 3];
        float a0 = T[(size_t)e0.x * D + lane];
        float a1 = T[(size_t)e1.x * D + lane];
        float a2 = T[(size_t)e2.x * D + lane];
        float a3 = T[(size_t)e3.x * D + lane];
        acc0 += __int_as_float(e0.y) * a0; acc1 += __int_as_float(e1.y) * a1;
        acc0 += __int_as_float(e2.y) * a2; acc1 += __int_as_float(e3.y) * a3;
    }
    for (; i < end; i++) {
        int2 e = edges[i];
        acc0 += __int_as_float(e.y) * T[(size_t)e.x * D + lane];
    }
    float h = fmaxf(acc0 + acc1 + bias[lane], 0.0f);
    if (FUSE_W3) {
        float p = h * W3[lane];
#pragma unroll
        for (int off = 32; off; off >>= 1) p += __shfl_xor(p, off);
        if (lane == 0) out[wave] = p;
    } else {
        out[(size_t)wave * D + lane] = h;
    }
}

// ---------------- layer 3: scalar aggregation + sigmoid (8-way ILP) ----------------
__global__ void k_agg3(const float* __restrict__ t3, const int* __restrict__ row_ptr,
                       const int2* __restrict__ edges, const float* __restrict__ dinv,
                       const float* __restrict__ b3, float* __restrict__ out, int n) {
    int v = blockIdx.x * blockDim.x + threadIdx.x;
    if (v >= n) return;
    float dv = dinv[v];
    float acc0 = dv * dv * t3[v];
    float acc1 = 0.0f;
    int beg = row_ptr[v], end = row_ptr[v + 1];
    int i = beg;
    for (; i + 8 <= end; i += 8) {
        int2 e0 = edges[i + 0], e1 = edges[i + 1], e2 = edges[i + 2], e3 = edges[i + 3];
        int2 e4 = edges[i + 4], e5 = edges[i + 5], e6 = edges[i + 6], e7 = edges[i + 7];
        float a0 = t3[e0.x], a1 = t3[e1.x], a2 = t3[e2.x], a3 = t3[e3.x];
        float a4 = t3[e4.x], a5 = t3[e5.x], a6 = t3[e6.x], a7 = t3[e7.x];
        acc0 += __int_as_float(e0.y) * a0; acc1 += __int_as_float(e1.y) * a1;
        acc0 += __int_as_float(e2.y) * a2; acc1 += __int_as_float(e3.y) * a3;
        acc0 += __int_as_float(e4.y) * a4; acc1 += __int_as_float(e5.y) * a5;
        acc0 += __int_as_float(e6.y) * a6; acc1 += __int_as_float(e7.y) * a7;
    }
    for (; i < end; i++) {
        int2 e = edges[i];
        acc0 += __int_as_float(e.y) * t3[e.x];
    }
    float z = acc0 + acc1 + b3[0];
    out[v] = 1.0f / (1.0f + expf(-z));
}

extern "C" void kernel_launch(void* const* d_in, const int* in_sizes, int n_in,
                              void* d_out, int out_size, void* d_ws, size_t ws_size,
                              hipStream_t stream) {
    const float* x  = (const float*)d_in[0];
    const int*   ei = (const int*)d_in[1];
    const float* w  = (const float*)d_in[2];
    const float* W1 = (const float*)d_in[3];
    const float* b1 = (const float*)d_in[4];
    const float* W2 = (const float*)d_in[5];
    const float* b2 = (const float*)d_in[6];
    const float* W3 = (const float*)d_in[7];
    const float* b3 = (const float*)d_in[8];
    float* out = (float*)d_out;

    const int N = NN, E = NE;
    const int* src = ei;
    const int* dst = ei + E;

    // workspace carve (256B aligned)
    char* p = (char*)d_ws;
    auto alloc = [&](size_t bytes) -> char* {
        char* r = p;
        p += (bytes + 255) & ~(size_t)255;
        return r;
    };
    float* deg     = (float*)alloc((size_t)N * 4);
    float* dinv    = (float*)alloc((size_t)N * 4);
    int*   counts  = (int*)alloc((size_t)N * 4);       // reused as scatter cursor
    int*   row_ptr = (int*)alloc((size_t)(N + 1) * 4);
    int*   partials= (int*)alloc(1024 * 4);
    int2*  edges   = (int2*)alloc((size_t)E * 8);      // packed (src, norm)
    float* bufA    = (float*)alloc((size_t)N * D * 4);
    float* bufB    = (float*)alloc((size_t)N * D * 4);
    float* t3      = (float*)alloc((size_t)N * 4);

    const int BT = 256;
    int gN  = (N + BT - 1) / BT;
    int gE  = (E + BT - 1) / BT;
    int nb  = (N + SCAN_B - 1) / SCAN_B;
    int gW  = (N * 64 + BT - 1) / BT;   // wave-per-node grids (4 waves/block)

    // --- graph prep ---
    k_init<<<gN, BT, 0, stream>>>(deg, counts, N);
    k_deg_count<<<gE, BT, 0, stream>>>(dst, w, deg, counts, E);
    k_dinv<<<gN, BT, 0, stream>>>(deg, dinv, N);
    k_scan1<<<nb, SCAN_B, 0, stream>>>(counts, row_ptr, partials, N);
    k_scan2<<<1, 64, 0, stream>>>(partials, nb);
    k_scan3<<<gN, BT, 0, stream>>>(row_ptr, partials, counts, N, E);
    k_scatter<<<gE, BT, 0, stream>>>(src, dst, w, dinv, counts, edges, E);

    // --- layer 1 ---
    k_gemm<<<gW, BT, 0, stream>>>(x, W1, bufA, N);
    k_agg<0><<<gW, BT, 0, stream>>>(bufA, row_ptr, edges, dinv, b1, nullptr, bufB, N);
    // --- layer 2 (fused h2 @ W3 epilogue -> t3) ---
    k_gemm<<<gW, BT, 0, stream>>>(bufB, W2, bufA, N);
    k_agg<1><<<gW, BT, 0, stream>>>(bufA, row_ptr, edges, dinv, b2, W3, t3, N);
    // --- layer 3: scalar aggregation + bias + sigmoid ---
    k_agg3<<<gN, BT, 0, stream>>>(t3, row_ptr, edges, dinv, b3, out, N);
}

// Round 5
// 519.748 us; speedup vs baseline: 1.6237x; 1.1881x over previous
//
#include <hip/hip_runtime.h>
#include <math.h>

#define NN 100000
#define NE 1600000
#define D 64
#define CAP 64            // padded-CSR slots per node; Poisson(16) max deg ~40 over 100k nodes
#define SCAN_B 1024

// ---------------- zero counts ----------------
__global__ void k_zero(int* __restrict__ cnt, int n) {
    int i = blockIdx.x * blockDim.x + threadIdx.x;
    if (i < n) cnt[i] = 0;
}

// ---------------- single-pass bucket scatter: cursor atomic IS the count ----------------
__global__ void k_bucket(const int* __restrict__ src, const int* __restrict__ dst,
                         const float* __restrict__ w, int* __restrict__ cnt,
                         int2* __restrict__ slots, int E) {
    int e = blockIdx.x * blockDim.x + threadIdx.x;
    if (e < E) {
        int d = dst[e];
        int p = atomicAdd(&cnt[d], 1);
        if (p < CAP)   // clamp: never corrupts memory; drop prob ~1e-13
            slots[(size_t)d * CAP + p] = make_int2(src[e], __float_as_int(w[e]));
    }
}

// ---------------- wave per node: deg = 1 + sum(w), dinv = rsqrt(deg), clamp cnt ----------------
__global__ void k_rowdeg(const int2* __restrict__ slots, int* __restrict__ cnt,
                         float* __restrict__ dinv, int n) {
    int wave = (int)((blockIdx.x * blockDim.x + threadIdx.x) >> 6);
    int lane = threadIdx.x & 63;
    if (wave >= n) return;
    int c = cnt[wave]; c = c < CAP ? c : CAP;
    float wv = (lane < c) ? __int_as_float(slots[(size_t)wave * CAP + lane].y) : 0.0f;
#pragma unroll
    for (int off = 32; off; off >>= 1) wv += __shfl_xor(wv, off);
    if (lane == 0) {
        cnt[wave] = c;
        dinv[wave] = rsqrtf(1.0f + wv);   // self-loop weight 1 => deg >= 1
    }
}

// ---------------- exclusive scan over cnt -> row_ptr ----------------
__global__ void k_scan1(const int* __restrict__ counts, int* __restrict__ row_ptr,
                        int* __restrict__ partials, int n) {
    __shared__ int sm[SCAN_B];
    int t = threadIdx.x;
    int i = blockIdx.x * SCAN_B + t;
    int v = (i < n) ? counts[i] : 0;
    sm[t] = v;
    __syncthreads();
    for (int off = 1; off < SCAN_B; off <<= 1) {
        int add = (t >= off) ? sm[t - off] : 0;
        __syncthreads();
        sm[t] += add;
        __syncthreads();
    }
    if (i < n) row_ptr[i] = sm[t] - v;                  // exclusive within block
    if (t == SCAN_B - 1) partials[blockIdx.x] = sm[t];  // block total
}

__global__ void k_scan2(int* __restrict__ partials, int nb) {
    if (threadIdx.x == 0 && blockIdx.x == 0) {
        int run = 0;
        for (int b = 0; b < nb; b++) { int t = partials[b]; partials[b] = run; run += t; }
        partials[nb] = run;   // grand total (may be < E only if a bucket overflowed)
    }
}

__global__ void k_scan3(int* __restrict__ row_ptr, const int* __restrict__ partials,
                        int n, int nb) {
    int i = blockIdx.x * blockDim.x + threadIdx.x;
    if (i < n) row_ptr[i] += partials[i / SCAN_B];
    if (i == 0) row_ptr[n] = partials[nb];
}

// ---------------- compact padded buckets -> CSR with fused norm ----------------
// thread per slot: coalesced slot reads, coalesced edge writes
__global__ void k_compact(const int2* __restrict__ slots, const int* __restrict__ cnt,
                          const int* __restrict__ row_ptr, const float* __restrict__ dinv,
                          int2* __restrict__ edges, int n) {
    int tid = blockIdx.x * blockDim.x + threadIdx.x;
    int v = tid >> 6;          // CAP == 64
    int j = tid & 63;
    if (v >= n) return;
    if (j < cnt[v]) {
        int2 sl = slots[(size_t)v * CAP + j];
        float nv = dinv[sl.x] * __int_as_float(sl.y) * dinv[v];
        edges[row_ptr[v] + j] = make_int2(sl.x, __float_as_int(nv));
    }
}

// ---------------- dense: T = X @ W  (per-wave row, W staged in LDS) ----------------
__global__ void k_gemm(const float* __restrict__ X, const float* __restrict__ W,
                       float* __restrict__ T, int n) {
    __shared__ float Ws[D * D];
    for (int i = threadIdx.x; i < D * D; i += blockDim.x) Ws[i] = W[i];
    __syncthreads();
    int wave = (int)((blockIdx.x * blockDim.x + threadIdx.x) >> 6);
    int lane = threadIdx.x & 63;
    if (wave >= n) return;
    float xv = X[(size_t)wave * D + lane];
    float acc = 0.0f;
#pragma unroll
    for (int k = 0; k < D; k++) acc += __shfl(xv, k) * Ws[k * D + lane];
    T[(size_t)wave * D + lane] = acc;
}

// ---------------- aggregation: out = relu(A*T + b) ; optional fused @W3 ----------------
// 8-way edge ILP: 8 independent 256B row gathers in flight per wave.
template <int FUSE_W3>
__global__ void k_agg(const float* __restrict__ T, const int* __restrict__ row_ptr,
                      const int2* __restrict__ edges, const float* __restrict__ dinv,
                      const float* __restrict__ bias, const float* __restrict__ W3,
                      float* __restrict__ out, int n) {
    int wave = (int)((blockIdx.x * blockDim.x + threadIdx.x) >> 6);
    int lane = threadIdx.x & 63;
    if (wave >= n) return;
    int beg = row_ptr[wave], end = row_ptr[wave + 1];
    float dv = dinv[wave];
    float acc0 = dv * dv * T[(size_t)wave * D + lane];   // self-loop term
    float acc1 = 0.0f;
    int i = beg;
    for (; i + 8 <= end; i += 8) {
        int2 e0 = edges[i + 0], e1 = edges[i + 1], e2 = edges[i + 2], e3 = edges[i + 3];
        int2 e4 = edges[i + 4], e5 = edges[i + 5], e6 = edges[i + 6], e7 = edges[i + 7];
        float a0 = T[(size_t)e0.x * D + lane];
        float a1 = T[(size_t)e1.x * D + lane];
        float a2 = T[(size_t)e2.x * D + lane];
        float a3 = T[(size_t)e3.x * D + lane];
        float a4 = T[(size_t)e4.x * D + lane];
        float a5 = T[(size_t)e5.x * D + lane];
        float a6 = T[(size_t)e6.x * D + lane];
        float a7 = T[(size_t)e7.x * D + lane];
        acc0 += __int_as_float(e0.y) * a0; acc1 += __int_as_float(e1.y) * a1;
        acc0 += __int_as_float(e2.y) * a2; acc1 += __int_as_float(e3.y) * a3;
        acc0 += __int_as_float(e4.y) * a4; acc1 += __int_as_float(e5.y) * a5;
        acc0 += __int_as_float(e6.y) * a6; acc1 += __int_as_float(e7.y) * a7;
    }
    for (; i + 4 <= end; i += 4) {
        int2 e0 = edges[i + 0], e1 = edges[i + 1], e2 = edges[i + 2], e3 = edges[i + 3];
        float a0 = T[(size_t)e0.x * D + lane];
        float a1 = T[(size_t)e1.x * D + lane];
        float a2 = T[(size_t)e2.x * D + lane];
        float a3 = T[(size_t)e3.x * D + lane];
        acc0 += __int_as_float(e0.y) * a0; acc1 += __int_as_float(e1.y) * a1;
        acc0 += __int_as_float(e2.y) * a2; acc1 += __int_as_float(e3.y) * a3;
    }
    for (; i < end; i++) {
        int2 e = edges[i];
        acc0 += __int_as_float(e.y) * T[(size_t)e.x * D + lane];
    }
    float h = fmaxf(acc0 + acc1 + bias[lane], 0.0f);
    if (FUSE_W3) {
        float p = h * W3[lane];
#pragma unroll
        for (int off = 32; off; off >>= 1) p += __shfl_xor(p, off);
        if (lane == 0) out[wave] = p;
    } else {
        out[(size_t)wave * D + lane] = h;
    }
}

// ---------------- layer 3: scalar aggregation + sigmoid (8-way ILP) ----------------
__global__ void k_agg3(const float* __restrict__ t3, const int* __restrict__ row_ptr,
                       const int2* __restrict__ edges, const float* __restrict__ dinv,
                       const float* __restrict__ b3, float* __restrict__ out, int n) {
    int v = blockIdx.x * blockDim.x + threadIdx.x;
    if (v >= n) return;
    float dv = dinv[v];
    float acc0 = dv * dv * t3[v];
    float acc1 = 0.0f;
    int beg = row_ptr[v], end = row_ptr[v + 1];
    int i = beg;
    for (; i + 8 <= end; i += 8) {
        int2 e0 = edges[i + 0], e1 = edges[i + 1], e2 = edges[i + 2], e3 = edges[i + 3];
        int2 e4 = edges[i + 4], e5 = edges[i + 5], e6 = edges[i + 6], e7 = edges[i + 7];
        float a0 = t3[e0.x], a1 = t3[e1.x], a2 = t3[e2.x], a3 = t3[e3.x];
        float a4 = t3[e4.x], a5 = t3[e5.x], a6 = t3[e6.x], a7 = t3[e7.x];
        acc0 += __int_as_float(e0.y) * a0; acc1 += __int_as_float(e1.y) * a1;
        acc0 += __int_as_float(e2.y) * a2; acc1 += __int_as_float(e3.y) * a3;
        acc0 += __int_as_float(e4.y) * a4; acc1 += __int_as_float(e5.y) * a5;
        acc0 += __int_as_float(e6.y) * a6; acc1 += __int_as_float(e7.y) * a7;
    }
    for (; i < end; i++) {
        int2 e = edges[i];
        acc0 += __int_as_float(e.y) * t3[e.x];
    }
    float z = acc0 + acc1 + b3[0];
    out[v] = 1.0f / (1.0f + expf(-z));
}

extern "C" void kernel_launch(void* const* d_in, const int* in_sizes, int n_in,
                              void* d_out, int out_size, void* d_ws, size_t ws_size,
                              hipStream_t stream) {
    const float* x  = (const float*)d_in[0];
    const int*   ei = (const int*)d_in[1];
    const float* w  = (const float*)d_in[2];
    const float* W1 = (const float*)d_in[3];
    const float* b1 = (const float*)d_in[4];
    const float* W2 = (const float*)d_in[5];
    const float* b2 = (const float*)d_in[6];
    const float* W3 = (const float*)d_in[7];
    const float* b3 = (const float*)d_in[8];
    float* out = (float*)d_out;

    const int N = NN, E = NE;
    const int* src = ei;
    const int* dst = ei + E;

    // workspace carve (256B aligned)
    char* p = (char*)d_ws;
    auto alloc = [&](size_t bytes) -> char* {
        char* r = p;
        p += (bytes + 255) & ~(size_t)255;
        return r;
    };
    float* dinv    = (float*)alloc((size_t)N * 4);
    int*   cnt     = (int*)alloc((size_t)N * 4);
    int*   row_ptr = (int*)alloc((size_t)(N + 1) * 4);
    int*   partials= (int*)alloc(1025 * 4);
    int2*  edges   = (int2*)alloc((size_t)E * 8);      // compact CSR (src, norm)
    float* bufA    = (float*)alloc((size_t)N * D * 4);
    float* bufB    = (float*)alloc((size_t)N * D * 4);
    float* t3      = (float*)alloc((size_t)N * 4);
    // padded buckets overlay bufA+bufB (N*CAP*8 = 51.2MB == bufA+bufB exactly);
    // buckets are dead before the first k_gemm writes bufA.
    int2* slots = (int2*)bufA;

    const int BT = 256;
    int gN  = (N + BT - 1) / BT;
    int gE  = (E + BT - 1) / BT;
    int nb  = (N + SCAN_B - 1) / SCAN_B;
    int gW  = (N * 64 + BT - 1) / BT;   // wave-per-node grids (4 waves/block)
    int gS  = (N * CAP + BT - 1) / BT;  // thread-per-slot grid

    // --- CSR build: one atomic + one store per edge ---
    k_zero<<<gN, BT, 0, stream>>>(cnt, N);
    k_bucket<<<gE, BT, 0, stream>>>(src, dst, w, cnt, slots, E);
    k_rowdeg<<<gW, BT, 0, stream>>>(slots, cnt, dinv, N);
    k_scan1<<<nb, SCAN_B, 0, stream>>>(cnt, row_ptr, partials, N);
    k_scan2<<<1, 64, 0, stream>>>(partials, nb);
    k_scan3<<<gN, BT, 0, stream>>>(row_ptr, partials, N, nb);
    k_compact<<<gS, BT, 0, stream>>>(slots, cnt, row_ptr, dinv, edges, N);

    // --- layer 1 ---
    k_gemm<<<gW, BT, 0, stream>>>(x, W1, bufA, N);
    k_agg<0><<<gW, BT, 0, stream>>>(bufA, row_ptr, edges, dinv, b1, nullptr, bufB, N);
    // --- layer 2 (fused h2 @ W3 epilogue -> t3) ---
    k_gemm<<<gW, BT, 0, stream>>>(bufB, W2, bufA, N);
    k_agg<1><<<gW, BT, 0, stream>>>(bufA, row_ptr, edges, dinv, b2, W3, t3, N);
    // --- layer 3: scalar aggregation + bias + sigmoid ---
    k_agg3<<<gN, BT, 0, stream>>>(t3, row_ptr, edges, dinv, b3, out, N);
}

// Round 6
// 434.634 us; speedup vs baseline: 1.9417x; 1.1958x over previous
//
#include <hip/hip_runtime.h>
#include <math.h>

#define NN 100000
#define NE 1600000
#define D 64
#define CAP 64            // slots per node; Poisson(16) max deg ~40 over 100k nodes
#define SCAN_B 1024

// ---------------- init slots to EMPTY (all ones) ----------------
__global__ void k_slot_init(int4* __restrict__ s, int n16) {
    int i = blockIdx.x * blockDim.x + threadIdx.x;
    if (i < n16) s[i] = make_int4(-1, -1, -1, -1);
}

// ---------------- hash-CAS scatter: ONE transaction per edge (exp. 1.17) ----------------
// record = (w_bits << 32) | src ; never equals ~0 since src >= 0.
__global__ void k_hash(const int* __restrict__ src, const int* __restrict__ dst,
                       const float* __restrict__ w,
                       unsigned long long* __restrict__ slots, int E) {
    int e = blockIdx.x * blockDim.x + threadIdx.x;
    if (e >= E) return;
    int d = dst[e];
    unsigned long long rec =
        ((unsigned long long)(unsigned)__float_as_int(w[e]) << 32) | (unsigned)src[e];
    size_t base = (size_t)d * CAP;
    unsigned h = (unsigned)e & (CAP - 1);          // random-ish start within bucket
    for (int t = 0; t < CAP; t++) {                // bounded probe; overflow drop prob ~1e-13
        unsigned long long old = atomicCAS(&slots[base + h], ~0ull, rec);
        if (old == ~0ull) return;
        h = (h + 1) & (CAP - 1);
    }
}

// ---------------- wave per node: count via ballot, deg = 1 + sum(w), dinv ----------------
__global__ void k_rowdeg(const int2* __restrict__ slots, int* __restrict__ cnt,
                         float* __restrict__ dinv, int n) {
    int wave = (int)((blockIdx.x * blockDim.x + threadIdx.x) >> 6);
    int lane = threadIdx.x & 63;
    if (wave >= n) return;
    int2 sl = slots[(size_t)wave * CAP + lane];
    bool occ = (sl.x != -1);
    unsigned long long mask = __ballot(occ);
    float wv = occ ? __int_as_float(sl.y) : 0.0f;
#pragma unroll
    for (int off = 32; off; off >>= 1) wv += __shfl_xor(wv, off);
    if (lane == 0) {
        cnt[wave] = __popcll(mask);
        dinv[wave] = rsqrtf(1.0f + wv);   // self-loop weight 1 => deg >= 1
    }
}

// ---------------- exclusive scan over cnt -> row_ptr ----------------
__global__ void k_scan1(const int* __restrict__ counts, int* __restrict__ row_ptr,
                        int* __restrict__ partials, int n) {
    __shared__ int sm[SCAN_B];
    int t = threadIdx.x;
    int i = blockIdx.x * SCAN_B + t;
    int v = (i < n) ? counts[i] : 0;
    sm[t] = v;
    __syncthreads();
    for (int off = 1; off < SCAN_B; off <<= 1) {
        int add = (t >= off) ? sm[t - off] : 0;
        __syncthreads();
        sm[t] += add;
        __syncthreads();
    }
    if (i < n) row_ptr[i] = sm[t] - v;                  // exclusive within block
    if (t == SCAN_B - 1) partials[blockIdx.x] = sm[t];  // block total
}

__global__ void k_scan2(int* __restrict__ partials, int nb) {
    if (threadIdx.x == 0 && blockIdx.x == 0) {
        int run = 0;
        for (int b = 0; b < nb; b++) { int t = partials[b]; partials[b] = run; run += t; }
        partials[nb] = run;   // grand total
    }
}

__global__ void k_scan3(int* __restrict__ row_ptr, const int* __restrict__ partials,
                        int n, int nb) {
    int i = blockIdx.x * blockDim.x + threadIdx.x;
    if (i < n) row_ptr[i] += partials[i / SCAN_B];
    if (i == 0) row_ptr[n] = partials[nb];
}

// ---------------- compact holey buckets -> CSR with fused norm (ballot-rank) ----------------
__global__ void k_compact(const int2* __restrict__ slots, const int* __restrict__ row_ptr,
                          const float* __restrict__ dinv, int2* __restrict__ edges, int n) {
    int wave = (int)((blockIdx.x * blockDim.x + threadIdx.x) >> 6);
    int lane = threadIdx.x & 63;
    if (wave >= n) return;
    int2 sl = slots[(size_t)wave * CAP + lane];
    bool occ = (sl.x != -1);
    unsigned long long mask = __ballot(occ);
    if (occ) {
        int rank = __popcll(mask & ((1ull << lane) - 1ull));
        float nv = dinv[sl.x] * __int_as_float(sl.y) * dinv[wave];
        edges[row_ptr[wave] + rank] = make_int2(sl.x, __float_as_int(nv));
    }
}

// ---------------- dense: T = X @ W  (wave-uniform scalar broadcast, W in VGPRs) ----------
// 4 rows per wave; X[r][k] is wave-uniform -> s_load; inner loop = 1 v_fmac/output.
__global__ void k_gemm(const float* __restrict__ X, const float* __restrict__ W,
                       float* __restrict__ T, int n) {
    int wid = (int)((blockIdx.x * blockDim.x + threadIdx.x) >> 6);
    int lane = threadIdx.x & 63;
    int r0 = wid * 4;
    if (r0 >= n) return;
    float wc[D];
#pragma unroll
    for (int k = 0; k < D; k++) wc[k] = W[k * D + lane];   // coalesced, L2-hot
#pragma unroll
    for (int rr = 0; rr < 4; rr++) {
        int r = r0 + rr;
        if (r >= n) break;
        const float* xr = X + (size_t)r * D;
        float acc = 0.0f;
#pragma unroll
        for (int k = 0; k < D; k++) acc += xr[k] * wc[k];  // uniform xr[k] -> scalar load
        T[(size_t)r * D + lane] = acc;
    }
}

// ---------------- aggregation: out = relu(A*T + b) ; optional fused @W3 ----------------
// 16-way edge ILP (compile-time-indexed regs), 8-way mid tier, scalar tail.
template <int FUSE_W3>
__global__ void k_agg(const float* __restrict__ T, const int* __restrict__ row_ptr,
                      const int2* __restrict__ edges, const float* __restrict__ dinv,
                      const float* __restrict__ bias, const float* __restrict__ W3,
                      float* __restrict__ out, int n) {
    int wave = (int)((blockIdx.x * blockDim.x + threadIdx.x) >> 6);
    int lane = threadIdx.x & 63;
    if (wave >= n) return;
    int beg = row_ptr[wave], end = row_ptr[wave + 1];
    float dv = dinv[wave];
    float acc0 = dv * dv * T[(size_t)wave * D + lane];   // self-loop term
    float acc1 = 0.0f;
    int i = beg;
    for (; i + 16 <= end; i += 16) {
        int2 er[16]; float av[16];
#pragma unroll
        for (int j = 0; j < 16; j++) er[j] = edges[i + j];
#pragma unroll
        for (int j = 0; j < 16; j++) av[j] = T[(size_t)er[j].x * D + lane];
#pragma unroll
        for (int j = 0; j < 16; j++) {
            if (j & 1) acc1 += __int_as_float(er[j].y) * av[j];
            else       acc0 += __int_as_float(er[j].y) * av[j];
        }
    }
    for (; i + 8 <= end; i += 8) {
        int2 er[8]; float av[8];
#pragma unroll
        for (int j = 0; j < 8; j++) er[j] = edges[i + j];
#pragma unroll
        for (int j = 0; j < 8; j++) av[j] = T[(size_t)er[j].x * D + lane];
#pragma unroll
        for (int j = 0; j < 8; j++) {
            if (j & 1) acc1 += __int_as_float(er[j].y) * av[j];
            else       acc0 += __int_as_float(er[j].y) * av[j];
        }
    }
    for (; i < end; i++) {
        int2 e = edges[i];
        acc0 += __int_as_float(e.y) * T[(size_t)e.x * D + lane];
    }
    float h = fmaxf(acc0 + acc1 + bias[lane], 0.0f);
    if (FUSE_W3) {
        float p = h * W3[lane];
#pragma unroll
        for (int off = 32; off; off >>= 1) p += __shfl_xor(p, off);
        if (lane == 0) out[wave] = p;
    } else {
        out[(size_t)wave * D + lane] = h;
    }
}

// ---------------- layer 3: scalar aggregation + sigmoid (8-way ILP) ----------------
__global__ void k_agg3(const float* __restrict__ t3, const int* __restrict__ row_ptr,
                       const int2* __restrict__ edges, const float* __restrict__ dinv,
                       const float* __restrict__ b3, float* __restrict__ out, int n) {
    int v = blockIdx.x * blockDim.x + threadIdx.x;
    if (v >= n) return;
    float dv = dinv[v];
    float acc0 = dv * dv * t3[v];
    float acc1 = 0.0f;
    int beg = row_ptr[v], end = row_ptr[v + 1];
    int i = beg;
    for (; i + 8 <= end; i += 8) {
        int2 er[8]; float av[8];
#pragma unroll
        for (int j = 0; j < 8; j++) er[j] = edges[i + j];
#pragma unroll
        for (int j = 0; j < 8; j++) av[j] = t3[er[j].x];
#pragma unroll
        for (int j = 0; j < 8; j++) {
            if (j & 1) acc1 += __int_as_float(er[j].y) * av[j];
            else       acc0 += __int_as_float(er[j].y) * av[j];
        }
    }
    for (; i < end; i++) {
        int2 e = edges[i];
        acc0 += __int_as_float(e.y) * t3[e.x];
    }
    float z = acc0 + acc1 + b3[0];
    out[v] = 1.0f / (1.0f + expf(-z));
}

extern "C" void kernel_launch(void* const* d_in, const int* in_sizes, int n_in,
                              void* d_out, int out_size, void* d_ws, size_t ws_size,
                              hipStream_t stream) {
    const float* x  = (const float*)d_in[0];
    const int*   ei = (const int*)d_in[1];
    const float* w  = (const float*)d_in[2];
    const float* W1 = (const float*)d_in[3];
    const float* b1 = (const float*)d_in[4];
    const float* W2 = (const float*)d_in[5];
    const float* b2 = (const float*)d_in[6];
    const float* W3 = (const float*)d_in[7];
    const float* b3 = (const float*)d_in[8];
    float* out = (float*)d_out;

    const int N = NN, E = NE;
    const int* src = ei;
    const int* dst = ei + E;

    // workspace carve (256B aligned)
    char* p = (char*)d_ws;
    auto alloc = [&](size_t bytes) -> char* {
        char* r = p;
        p += (bytes + 255) & ~(size_t)255;
        return r;
    };
    float* dinv    = (float*)alloc((size_t)N * 4);
    int*   cnt     = (int*)alloc((size_t)N * 4);
    int*   row_ptr = (int*)alloc((size_t)(N + 1) * 4);
    int*   partials= (int*)alloc(1026 * 4);
    int2*  edges   = (int2*)alloc((size_t)E * 8);      // compact CSR (src, norm)
    float* bufA    = (float*)alloc((size_t)N * D * 4);
    float* bufB    = (float*)alloc((size_t)N * D * 4);
    float* t3      = (float*)alloc((size_t)N * 4);
    // hash buckets overlay bufA+bufB (N*CAP*8 = 51.2MB == bufA+bufB exactly);
    // buckets are dead before the first k_gemm writes bufA.
    unsigned long long* slots = (unsigned long long*)bufA;

    const int BT = 256;
    int gN  = (N + BT - 1) / BT;
    int gE  = (E + BT - 1) / BT;
    int nb  = (N + SCAN_B - 1) / SCAN_B;
    int gW  = (N * 64 + BT - 1) / BT;          // wave-per-node grids (4 waves/block)
    int gG  = (N + 15) / 16;                   // gemm: 4 waves/block * 4 rows/wave
    int n16 = (int)((size_t)N * CAP * 8 / 16); // int4 count for slot init
    int gI  = (n16 + BT - 1) / BT;

    // --- CSR build: ~1 transaction per edge ---
    k_slot_init<<<gI, BT, 0, stream>>>((int4*)slots, n16);
    k_hash<<<gE, BT, 0, stream>>>(src, dst, w, slots, E);
    k_rowdeg<<<gW, BT, 0, stream>>>((const int2*)slots, cnt, dinv, N);
    k_scan1<<<nb, SCAN_B, 0, stream>>>(cnt, row_ptr, partials, N);
    k_scan2<<<1, 64, 0, stream>>>(partials, nb);
    k_scan3<<<gN, BT, 0, stream>>>(row_ptr, partials, N, nb);
    k_compact<<<gW, BT, 0, stream>>>((const int2*)slots, row_ptr, dinv, edges, N);

    // --- layer 1 ---
    k_gemm<<<gG, BT, 0, stream>>>(x, W1, bufA, N);
    k_agg<0><<<gW, BT, 0, stream>>>(bufA, row_ptr, edges, dinv, b1, nullptr, bufB, N);
    // --- layer 2 (fused h2 @ W3 epilogue -> t3) ---
    k_gemm<<<gG, BT, 0, stream>>>(bufB, W2, bufA, N);
    k_agg<1><<<gW, BT, 0, stream>>>(bufA, row_ptr, edges, dinv, b2, W3, t3, N);
    // --- layer 3: scalar aggregation + bias + sigmoid ---
    k_agg3<<<gN, BT, 0, stream>>>(t3, row_ptr, edges, dinv, b3, out, N);
}

// Round 7
// 377.698 us; speedup vs baseline: 2.2344x; 1.1507x over previous
//
#include <hip/hip_runtime.h>
#include <hip/hip_fp16.h>
#include <math.h>

#define NN 100000
#define NE 1600000
#define D 64
#define CAP 64            // slots per node; Poisson(16) max deg ~40 over 100k nodes
#define SCAN_B 1024

// ---------------- init slots to EMPTY (all ones) ----------------
__global__ void k_slot_init(int4* __restrict__ s, int n16) {
    int i = blockIdx.x * blockDim.x + threadIdx.x;
    if (i < n16) s[i] = make_int4(-1, -1, -1, -1);
}

// ---------------- hash-CAS scatter: ONE transaction per edge (exp. 1.17) ----------------
// record = (w_bits << 32) | src ; never equals ~0 since src >= 0.
__global__ void k_hash(const int* __restrict__ src, const int* __restrict__ dst,
                       const float* __restrict__ w,
                       unsigned long long* __restrict__ slots, int E) {
    int e = blockIdx.x * blockDim.x + threadIdx.x;
    if (e >= E) return;
    int d = dst[e];
    unsigned long long rec =
        ((unsigned long long)(unsigned)__float_as_int(w[e]) << 32) | (unsigned)src[e];
    size_t base = (size_t)d * CAP;
    unsigned h = (unsigned)e & (CAP - 1);
    for (int t = 0; t < CAP; t++) {                // bounded probe
        unsigned long long old = atomicCAS(&slots[base + h], ~0ull, rec);
        if (old == ~0ull) return;
        h = (h + 1) & (CAP - 1);
    }
}

// ---------------- wave per node: count via ballot, deg = 1 + sum(w), dinv ----------------
__global__ void k_rowdeg(const int2* __restrict__ slots, int* __restrict__ cnt,
                         float* __restrict__ dinv, int n) {
    int wave = (int)((blockIdx.x * blockDim.x + threadIdx.x) >> 6);
    int lane = threadIdx.x & 63;
    if (wave >= n) return;
    int2 sl = slots[(size_t)wave * CAP + lane];
    bool occ = (sl.x != -1);
    unsigned long long mask = __ballot(occ);
    float wv = occ ? __int_as_float(sl.y) : 0.0f;
#pragma unroll
    for (int off = 32; off; off >>= 1) wv += __shfl_xor(wv, off);
    if (lane == 0) {
        cnt[wave] = __popcll(mask);
        dinv[wave] = rsqrtf(1.0f + wv);   // self-loop weight 1 => deg >= 1
    }
}

// ---------------- exclusive scan over cnt -> row_ptr (block-local) ----------------
__global__ void k_scan1(const int* __restrict__ counts, int* __restrict__ row_ptr,
                        int* __restrict__ partials, int n) {
    __shared__ int sm[SCAN_B];
    int t = threadIdx.x;
    int i = blockIdx.x * SCAN_B + t;
    int v = (i < n) ? counts[i] : 0;
    sm[t] = v;
    __syncthreads();
    for (int off = 1; off < SCAN_B; off <<= 1) {
        int add = (t >= off) ? sm[t - off] : 0;
        __syncthreads();
        sm[t] += add;
        __syncthreads();
    }
    if (i < n) row_ptr[i] = sm[t] - v;                  // exclusive within block
    if (t == SCAN_B - 1) partials[blockIdx.x] = sm[t];  // block total
}

// 128-thread block scan over the <=128 partials (exclusive) + grand total
__global__ void k_scan2(int* __restrict__ partials, int nb) {
    __shared__ int sm[128];
    int t = threadIdx.x;
    int v = (t < nb) ? partials[t] : 0;
    sm[t] = v;
    __syncthreads();
    for (int off = 1; off < 128; off <<= 1) {
        int add = (t >= off) ? sm[t - off] : 0;
        __syncthreads();
        sm[t] += add;
        __syncthreads();
    }
    if (t < nb) partials[t] = sm[t] - v;   // exclusive
    if (t == 127) partials[nb] = sm[127];  // grand total
}

// ---------------- compact: applies partials, writes final row_ptr + CSR+norm ----------------
__global__ void k_compact(const int2* __restrict__ slots, const float* __restrict__ dinv,
                          const int* __restrict__ partials, int2* __restrict__ edges,
                          int* __restrict__ row_ptr, int n, int nb) {
    int wave = (int)((blockIdx.x * blockDim.x + threadIdx.x) >> 6);
    int lane = threadIdx.x & 63;
    if (wave >= n) return;
    int2 sl = slots[(size_t)wave * CAP + lane];
    bool occ = (sl.x != -1);
    unsigned long long mask = __ballot(occ);
    int base = row_ptr[wave] + partials[wave >> 10];   // SCAN_B == 1024
    if (lane == 0) {
        row_ptr[wave] = base;
        if (wave == 0) row_ptr[n] = partials[nb];
    }
    if (occ) {
        int rank = __popcll(mask & ((1ull << lane) - 1ull));
        float nv = dinv[sl.x] * __int_as_float(sl.y) * dinv[wave];
        edges[base + rank] = make_int2(sl.x, __float_as_int(nv));
    }
}

// ---------------- dense: T2 = X @ W, output packed half2 (lane pair c -> ch 2c,2c+1) ----
template <int IN_HALF>
__global__ void k_gemm(const void* __restrict__ Xv, const float* __restrict__ W,
                       __half2* __restrict__ T2, int n) {
    int wid = (int)((blockIdx.x * blockDim.x + threadIdx.x) >> 6);
    int lane = threadIdx.x & 63;
    int c = lane & 31;
    int r0 = wid * 4;
    if (r0 >= n) return;
    float wc[D];
#pragma unroll
    for (int k = 0; k < D; k++) wc[k] = W[k * D + lane];   // coalesced, L2-hot
#pragma unroll
    for (int rr = 0; rr < 4; rr++) {
        int r = r0 + rr;
        if (r >= n) break;
        float acc = 0.0f;
        if (IN_HALF) {
            const __half2* x2 = (const __half2*)Xv + (size_t)r * 32;
#pragma unroll
            for (int k2 = 0; k2 < 32; k2++) {
                float2 f = __half22float2(x2[k2]);     // wave-broadcast load
                acc += f.x * wc[2 * k2] + f.y * wc[2 * k2 + 1];
            }
        } else {
            const float* xf = (const float*)Xv + (size_t)r * D;
#pragma unroll
            for (int k = 0; k < D; k++) acc += xf[k] * wc[k];
        }
        float a0 = __shfl(acc, 2 * c);
        float a1 = __shfl(acc, 2 * c + 1);
        if (lane < 32) T2[(size_t)r * 32 + c] = __floats2half2_rn(a0, a1);
    }
}

// ---------------- aggregation on fp16 rows: out = relu(A*T + b) ; optional fused @W3 ----
// Lane owns channel pair c=lane&31; half-waves process even/odd edges (2 gathers of
// 128B in flight per step, 8-deep ILP per half = 16 edges in flight per wave).
template <int FUSE_W3>
__global__ void k_agg(const __half2* __restrict__ T2, const int* __restrict__ row_ptr,
                      const int2* __restrict__ edges, const float* __restrict__ dinv,
                      const float* __restrict__ bias, const float* __restrict__ W3,
                      void* __restrict__ outv, int n) {
    int wave = (int)((blockIdx.x * blockDim.x + threadIdx.x) >> 6);
    int lane = threadIdx.x & 63;
    if (wave >= n) return;
    int c = lane & 31;
    int h = lane >> 5;
    int beg = row_ptr[wave], end = row_ptr[wave + 1];
    float ax = 0.0f, ay = 0.0f, bx = 0.0f, by = 0.0f;
    int i = beg;
    for (; i + 16 <= end; i += 16) {
        int2 er[8];
#pragma unroll
        for (int j = 0; j < 8; j++) er[j] = edges[i + 2 * j + h];
        __half2 tv[8];
#pragma unroll
        for (int j = 0; j < 8; j++) tv[j] = T2[(size_t)er[j].x * 32 + c];
#pragma unroll
        for (int j = 0; j < 8; j++) {
            float nv = __int_as_float(er[j].y);
            float2 f = __half22float2(tv[j]);
            if (j & 1) { bx += nv * f.x; by += nv * f.y; }
            else       { ax += nv * f.x; ay += nv * f.y; }
        }
    }
    for (; i + 2 <= end; i += 2) {
        int2 e = edges[i + h];
        float nv = __int_as_float(e.y);
        float2 f = __half22float2(T2[(size_t)e.x * 32 + c]);
        ax += nv * f.x; ay += nv * f.y;
    }
    if (i < end && h == 0) {                       // odd leftover: half 0 only
        int2 e = edges[i];
        float nv = __int_as_float(e.y);
        float2 f = __half22float2(T2[(size_t)e.x * 32 + c]);
        ax += nv * f.x; ay += nv * f.y;
    }
    ax += bx; ay += by;
    ax += __shfl_xor(ax, 32);                      // combine halves
    ay += __shfl_xor(ay, 32);
    float dv = dinv[wave];
    float2 self = __half22float2(T2[(size_t)wave * 32 + c]);
    float hx = fmaxf(ax + dv * dv * self.x + bias[2 * c], 0.0f);
    float hy = fmaxf(ay + dv * dv * self.y + bias[2 * c + 1], 0.0f);
    if (FUSE_W3) {
        float pp = hx * W3[2 * c] + hy * W3[2 * c + 1];
#pragma unroll
        for (int off = 16; off; off >>= 1) pp += __shfl_xor(pp, off);
        if (lane == 0) ((float*)outv)[wave] = pp;
    } else {
        if (lane < 32) ((__half2*)outv)[(size_t)wave * 32 + c] = __floats2half2_rn(hx, hy);
    }
}

// ---------------- layer 3: scalar aggregation + sigmoid (8-way ILP, fp32) ----------------
__global__ void k_agg3(const float* __restrict__ t3, const int* __restrict__ row_ptr,
                       const int2* __restrict__ edges, const float* __restrict__ dinv,
                       const float* __restrict__ b3, float* __restrict__ out, int n) {
    int v = blockIdx.x * blockDim.x + threadIdx.x;
    if (v >= n) return;
    float dv = dinv[v];
    float acc0 = dv * dv * t3[v];
    float acc1 = 0.0f;
    int beg = row_ptr[v], end = row_ptr[v + 1];
    int i = beg;
    for (; i + 8 <= end; i += 8) {
        int2 er[8]; float av[8];
#pragma unroll
        for (int j = 0; j < 8; j++) er[j] = edges[i + j];
#pragma unroll
        for (int j = 0; j < 8; j++) av[j] = t3[er[j].x];
#pragma unroll
        for (int j = 0; j < 8; j++) {
            if (j & 1) acc1 += __int_as_float(er[j].y) * av[j];
            else       acc0 += __int_as_float(er[j].y) * av[j];
        }
    }
    for (; i < end; i++) {
        int2 e = edges[i];
        acc0 += __int_as_float(e.y) * t3[e.x];
    }
    float z = acc0 + acc1 + b3[0];
    out[v] = 1.0f / (1.0f + expf(-z));
}

extern "C" void kernel_launch(void* const* d_in, const int* in_sizes, int n_in,
                              void* d_out, int out_size, void* d_ws, size_t ws_size,
                              hipStream_t stream) {
    const float* x  = (const float*)d_in[0];
    const int*   ei = (const int*)d_in[1];
    const float* w  = (const float*)d_in[2];
    const float* W1 = (const float*)d_in[3];
    const float* b1 = (const float*)d_in[4];
    const float* W2 = (const float*)d_in[5];
    const float* b2 = (const float*)d_in[6];
    const float* W3 = (const float*)d_in[7];
    const float* b3 = (const float*)d_in[8];
    float* out = (float*)d_out;

    const int N = NN, E = NE;
    const int* src = ei;
    const int* dst = ei + E;

    // workspace carve (256B aligned)
    char* p = (char*)d_ws;
    auto alloc = [&](size_t bytes) -> char* {
        char* r = p;
        p += (bytes + 255) & ~(size_t)255;
        return r;
    };
    float* dinv    = (float*)alloc((size_t)N * 4);
    int*   cnt     = (int*)alloc((size_t)N * 4);
    int*   row_ptr = (int*)alloc((size_t)(N + 1) * 4);
    int*   partials= (int*)alloc(1028 * 4);
    int2*  edges   = (int2*)alloc((size_t)E * 8);       // compact CSR (src, norm)
    char*  slotreg = alloc((size_t)N * CAP * 8);        // 51.2 MB hash buckets
    float* t3      = (float*)alloc((size_t)N * 4);
    // fp16 feature buffers overlay the (dead-after-compact) slot region:
    unsigned long long* slots = (unsigned long long*)slotreg;
    __half2* bufA = (__half2*)slotreg;                          // N*32*4 = 12.8 MB
    __half2* bufB = (__half2*)(slotreg + (size_t)N * 32 * 4);   // next 12.8 MB

    const int BT = 256;
    int gN  = (N + BT - 1) / BT;
    int gE  = (E + BT - 1) / BT;
    int nb  = (N + SCAN_B - 1) / SCAN_B;
    int gW  = (N * 64 + BT - 1) / BT;          // wave-per-node grids (4 waves/block)
    int gG  = (N + 15) / 16;                   // gemm: 4 waves/block * 4 rows/wave
    int n16 = (int)((size_t)N * CAP * 8 / 16); // int4 count for slot init
    int gI  = (n16 + BT - 1) / BT;

    // --- CSR build: ~1 transaction per edge ---
    k_slot_init<<<gI, BT, 0, stream>>>((int4*)slots, n16);
    k_hash<<<gE, BT, 0, stream>>>(src, dst, w, slots, E);
    k_rowdeg<<<gW, BT, 0, stream>>>((const int2*)slots, cnt, dinv, N);
    k_scan1<<<nb, SCAN_B, 0, stream>>>(cnt, row_ptr, partials, N);
    k_scan2<<<1, 128, 0, stream>>>(partials, nb);
    k_compact<<<gW, BT, 0, stream>>>((const int2*)slots, dinv, partials, edges, row_ptr, N, nb);

    // --- layer 1 ---
    k_gemm<0><<<gG, BT, 0, stream>>>(x, W1, bufA, N);
    k_agg<0><<<gW, BT, 0, stream>>>(bufA, row_ptr, edges, dinv, b1, nullptr, bufB, N);
    // --- layer 2 (fused h2 @ W3 epilogue -> t3) ---
    k_gemm<1><<<gG, BT, 0, stream>>>(bufB, W2, bufA, N);
    k_agg<1><<<gW, BT, 0, stream>>>(bufA, row_ptr, edges, dinv, b2, W3, t3, N);
    // --- layer 3: scalar aggregation + bias + sigmoid ---
    k_agg3<<<gN, BT, 0, stream>>>(t3, row_ptr, edges, dinv, b3, out, N);
}

// Round 8
// 336.072 us; speedup vs baseline: 2.5112x; 1.1239x over previous
//
#include <hip/hip_runtime.h>
#include <hip/hip_fp16.h>
#include <math.h>

#define NN 100000
#define NE 1600000
#define D 64
#define BSH 8                         // bin = dst >> 8  (256 nodes/bin)
#define NBIN 391                      // ceil(100000/256)
#define EB 8192                       // edges per binning block
#define NBB ((NE + EB - 1) / EB)      // 196

// ---------------- pass A: per-block bin histogram (LDS atomics only) ----------------
__global__ void k_binhist(const int* __restrict__ dst, int* __restrict__ counts, int E) {
    __shared__ int h[NBIN];
    for (int i = threadIdx.x; i < NBIN; i += blockDim.x) h[i] = 0;
    __syncthreads();
    int e0 = blockIdx.x * EB;
    int e1 = min(e0 + EB, E);
    for (int e = e0 + threadIdx.x; e < e1; e += blockDim.x)
        atomicAdd(&h[dst[e] >> BSH], 1);
    __syncthreads();
    for (int i = threadIdx.x; i < NBIN; i += blockDim.x)
        counts[blockIdx.x * NBIN + i] = h[i];
}

// ---------------- scan: per-bin prefix over blocks + bin bases ----------------
__global__ void k_binscan(int* __restrict__ counts, int* __restrict__ binStart) {
    __shared__ int tot[512];
    int b = threadIdx.x;
    int sum = 0;
    if (b < NBIN) {
#pragma unroll 8
        for (int k = 0; k < NBB; k++) {
            int idx = k * NBIN + b;           // coalesced across b
            int c = counts[idx];
            counts[idx] = sum;                // exclusive per-block prefix
            sum += c;
        }
    }
    tot[b] = (b < NBIN) ? sum : 0;
    __syncthreads();
    int v = tot[b];
    for (int off = 1; off < 512; off <<= 1) {
        int add = (b >= off) ? tot[b - off] : 0;
        __syncthreads();
        tot[b] += add;
        __syncthreads();
    }
    if (b < NBIN) binStart[b] = tot[b] - v;   // exclusive bin base
    if (b == NBIN - 1) binStart[NBIN] = tot[b];  // == E
}

// ---------------- pass B: scatter edges into bin-contiguous order ----------------
// record: x = (dst_low8 << 17) | src17 ; y = w bits. LDS cursors, plain stores.
__global__ void k_binscatter(const int* __restrict__ src, const int* __restrict__ dst,
                             const float* __restrict__ w, const int* __restrict__ counts,
                             const int* __restrict__ binStart, int2* __restrict__ binned,
                             int E) {
    __shared__ int cur[NBIN];
    for (int i = threadIdx.x; i < NBIN; i += blockDim.x)
        cur[i] = binStart[i] + counts[blockIdx.x * NBIN + i];
    __syncthreads();
    int e0 = blockIdx.x * EB;
    int e1 = min(e0 + EB, E);
    for (int e = e0 + threadIdx.x; e < e1; e += blockDim.x) {
        int d = dst[e];
        int pos = atomicAdd(&cur[d >> BSH], 1);
        binned[pos] = make_int2(((d & 255) << 17) | src[e], __float_as_int(w[e]));
    }
}

// ---------------- C1: per-bin deg/dinv + final row_ptr (LDS only) ----------------
__global__ void k_deg(const int2* __restrict__ binned, const int* __restrict__ binStart,
                      float* __restrict__ dinv, int* __restrict__ row_ptr, int n) {
    __shared__ int   cnt[256];
    __shared__ float ws[256];
    __shared__ int   off[256];
    int b = blockIdx.x, t = threadIdx.x;
    cnt[t] = 0; ws[t] = 0.0f;
    __syncthreads();
    int e0 = binStart[b], e1 = binStart[b + 1];
    for (int e = e0 + t; e < e1; e += 256) {
        int2 r = binned[e];
        int dlow = (unsigned)r.x >> 17;
        atomicAdd(&cnt[dlow], 1);
        atomicAdd(&ws[dlow], __int_as_float(r.y));
    }
    __syncthreads();
    int v = cnt[t];
    off[t] = v;
    __syncthreads();
    for (int o = 1; o < 256; o <<= 1) {
        int add = (t >= o) ? off[t - o] : 0;
        __syncthreads();
        off[t] += add;
        __syncthreads();
    }
    int node = b * 256 + t;
    if (node < n) {
        dinv[node] = rsqrtf(1.0f + ws[t]);       // self-loop weight 1
        row_ptr[node] = e0 + off[t] - v;          // exclusive
    }
    if (b == NBIN - 1 && t == 0) row_ptr[n] = binStart[NBIN];
}

// ---------------- C2: per-bin rank + fused norm -> compact CSR ----------------
__global__ void k_csr(const int2* __restrict__ binned, const int* __restrict__ binStart,
                      const int* __restrict__ row_ptr, const float* __restrict__ dinv,
                      int2* __restrict__ edges, int n) {
    __shared__ int   rp[256];
    __shared__ int   cur[256];
    __shared__ float dd[256];
    int b = blockIdx.x, t = threadIdx.x;
    int node = b * 256 + t;
    rp[t]  = (node < n) ? row_ptr[node] : 0;
    dd[t]  = (node < n) ? dinv[node] : 0.0f;
    cur[t] = 0;
    __syncthreads();
    int e0 = binStart[b], e1 = binStart[b + 1];
    for (int e = e0 + t; e < e1; e += 256) {
        int2 r = binned[e];
        int dlow = (unsigned)r.x >> 17;
        int s = r.x & 0x1FFFF;
        int rank = atomicAdd(&cur[dlow], 1);
        float nv = dinv[s] * __int_as_float(r.y) * dd[dlow];
        edges[rp[dlow] + rank] = make_int2(s, __float_as_int(nv));
    }
}

// ---------------- dense: T2 = X @ W, output packed half2 (lane pair c -> ch 2c,2c+1) ----
template <int IN_HALF>
__global__ void k_gemm(const void* __restrict__ Xv, const float* __restrict__ W,
                       __half2* __restrict__ T2, int n) {
    int wid = (int)((blockIdx.x * blockDim.x + threadIdx.x) >> 6);
    int lane = threadIdx.x & 63;
    int c = lane & 31;
    int r0 = wid * 4;
    if (r0 >= n) return;
    float wc[D];
#pragma unroll
    for (int k = 0; k < D; k++) wc[k] = W[k * D + lane];   // coalesced, L2-hot
#pragma unroll
    for (int rr = 0; rr < 4; rr++) {
        int r = r0 + rr;
        if (r >= n) break;
        float acc = 0.0f;
        if (IN_HALF) {
            const __half2* x2 = (const __half2*)Xv + (size_t)r * 32;
#pragma unroll
            for (int k2 = 0; k2 < 32; k2++) {
                float2 f = __half22float2(x2[k2]);     // wave-broadcast load
                acc += f.x * wc[2 * k2] + f.y * wc[2 * k2 + 1];
            }
        } else {
            const float* xf = (const float*)Xv + (size_t)r * D;
#pragma unroll
            for (int k = 0; k < D; k++) acc += xf[k] * wc[k];
        }
        float a0 = __shfl(acc, 2 * c);
        float a1 = __shfl(acc, 2 * c + 1);
        if (lane < 32) T2[(size_t)r * 32 + c] = __floats2half2_rn(a0, a1);
    }
}

// ---------------- aggregation on fp16 rows: out = relu(A*T + b) ; optional fused @W3 ----
template <int FUSE_W3>
__global__ void k_agg(const __half2* __restrict__ T2, const int* __restrict__ row_ptr,
                      const int2* __restrict__ edges, const float* __restrict__ dinv,
                      const float* __restrict__ bias, const float* __restrict__ W3,
                      void* __restrict__ outv, int n) {
    int wave = (int)((blockIdx.x * blockDim.x + threadIdx.x) >> 6);
    int lane = threadIdx.x & 63;
    if (wave >= n) return;
    int c = lane & 31;
    int h = lane >> 5;
    int beg = row_ptr[wave], end = row_ptr[wave + 1];
    float ax = 0.0f, ay = 0.0f, bx = 0.0f, by = 0.0f;
    int i = beg;
    for (; i + 16 <= end; i += 16) {
        int2 er[8];
#pragma unroll
        for (int j = 0; j < 8; j++) er[j] = edges[i + 2 * j + h];
        __half2 tv[8];
#pragma unroll
        for (int j = 0; j < 8; j++) tv[j] = T2[(size_t)er[j].x * 32 + c];
#pragma unroll
        for (int j = 0; j < 8; j++) {
            float nv = __int_as_float(er[j].y);
            float2 f = __half22float2(tv[j]);
            if (j & 1) { bx += nv * f.x; by += nv * f.y; }
            else       { ax += nv * f.x; ay += nv * f.y; }
        }
    }
    for (; i + 2 <= end; i += 2) {
        int2 e = edges[i + h];
        float nv = __int_as_float(e.y);
        float2 f = __half22float2(T2[(size_t)e.x * 32 + c]);
        ax += nv * f.x; ay += nv * f.y;
    }
    if (i < end && h == 0) {                       // odd leftover: half 0 only
        int2 e = edges[i];
        float nv = __int_as_float(e.y);
        float2 f = __half22float2(T2[(size_t)e.x * 32 + c]);
        ax += nv * f.x; ay += nv * f.y;
    }
    ax += bx; ay += by;
    ax += __shfl_xor(ax, 32);                      // combine halves
    ay += __shfl_xor(ay, 32);
    float dv = dinv[wave];
    float2 self = __half22float2(T2[(size_t)wave * 32 + c]);
    float hx = fmaxf(ax + dv * dv * self.x + bias[2 * c], 0.0f);
    float hy = fmaxf(ay + dv * dv * self.y + bias[2 * c + 1], 0.0f);
    if (FUSE_W3) {
        float pp = hx * W3[2 * c] + hy * W3[2 * c + 1];
#pragma unroll
        for (int off = 16; off; off >>= 1) pp += __shfl_xor(pp, off);
        if (lane == 0) ((float*)outv)[wave] = pp;
    } else {
        if (lane < 32) ((__half2*)outv)[(size_t)wave * 32 + c] = __floats2half2_rn(hx, hy);
    }
}

// ---------------- layer 3: scalar aggregation + sigmoid (8-way ILP, fp32) ----------------
__global__ void k_agg3(const float* __restrict__ t3, const int* __restrict__ row_ptr,
                       const int2* __restrict__ edges, const float* __restrict__ dinv,
                       const float* __restrict__ b3, float* __restrict__ out, int n) {
    int v = blockIdx.x * blockDim.x + threadIdx.x;
    if (v >= n) return;
    float dv = dinv[v];
    float acc0 = dv * dv * t3[v];
    float acc1 = 0.0f;
    int beg = row_ptr[v], end = row_ptr[v + 1];
    int i = beg;
    for (; i + 8 <= end; i += 8) {
        int2 er[8]; float av[8];
#pragma unroll
        for (int j = 0; j < 8; j++) er[j] = edges[i + j];
#pragma unroll
        for (int j = 0; j < 8; j++) av[j] = t3[er[j].x];
#pragma unroll
        for (int j = 0; j < 8; j++) {
            if (j & 1) acc1 += __int_as_float(er[j].y) * av[j];
            else       acc0 += __int_as_float(er[j].y) * av[j];
        }
    }
    for (; i < end; i++) {
        int2 e = edges[i];
        acc0 += __int_as_float(e.y) * t3[e.x];
    }
    float z = acc0 + acc1 + b3[0];
    out[v] = 1.0f / (1.0f + expf(-z));
}

extern "C" void kernel_launch(void* const* d_in, const int* in_sizes, int n_in,
                              void* d_out, int out_size, void* d_ws, size_t ws_size,
                              hipStream_t stream) {
    const float* x  = (const float*)d_in[0];
    const int*   ei = (const int*)d_in[1];
    const float* w  = (const float*)d_in[2];
    const float* W1 = (const float*)d_in[3];
    const float* b1 = (const float*)d_in[4];
    const float* W2 = (const float*)d_in[5];
    const float* b2 = (const float*)d_in[6];
    const float* W3 = (const float*)d_in[7];
    const float* b3 = (const float*)d_in[8];
    float* out = (float*)d_out;

    const int N = NN, E = NE;
    const int* src = ei;
    const int* dst = ei + E;

    // workspace carve (256B aligned)
    char* p = (char*)d_ws;
    auto alloc = [&](size_t bytes) -> char* {
        char* r = p;
        p += (bytes + 255) & ~(size_t)255;
        return r;
    };
    float* dinv    = (float*)alloc((size_t)N * 4);
    int*   row_ptr = (int*)alloc((size_t)(N + 1) * 4);
    int*   binStart= (int*)alloc((NBIN + 1) * 4);
    int*   counts  = (int*)alloc((size_t)NBB * NBIN * 4);
    int2*  binned  = (int2*)alloc((size_t)E * 8);       // bin-ordered records
    int2*  edges   = (int2*)alloc((size_t)E * 8);       // compact CSR (src, norm)
    __half2* bufA  = (__half2*)alloc((size_t)N * 32 * 4);
    __half2* bufB  = (__half2*)alloc((size_t)N * 32 * 4);
    float* t3      = (float*)alloc((size_t)N * 4);

    const int BT = 256;
    int gN = (N + BT - 1) / BT;
    int gW = (N * 64 + BT - 1) / BT;          // wave-per-node grids (4 waves/block)
    int gG = (N + 15) / 16;                   // gemm: 4 waves/block * 4 rows/wave

    // --- CSR build: zero global atomics ---
    k_binhist<<<NBB, BT, 0, stream>>>(dst, counts, E);
    k_binscan<<<1, 512, 0, stream>>>(counts, binStart);
    k_binscatter<<<NBB, BT, 0, stream>>>(src, dst, w, counts, binStart, binned, E);
    k_deg<<<NBIN, BT, 0, stream>>>(binned, binStart, dinv, row_ptr, N);
    k_csr<<<NBIN, BT, 0, stream>>>(binned, binStart, row_ptr, dinv, edges, N);

    // --- layer 1 ---
    k_gemm<0><<<gG, BT, 0, stream>>>(x, W1, bufA, N);
    k_agg<0><<<gW, BT, 0, stream>>>(bufA, row_ptr, edges, dinv, b1, nullptr, bufB, N);
    // --- layer 2 (fused h2 @ W3 epilogue -> t3) ---
    k_gemm<1><<<gG, BT, 0, stream>>>(bufB, W2, bufA, N);
    k_agg<1><<<gW, BT, 0, stream>>>(bufA, row_ptr, edges, dinv, b2, W3, t3, N);
    // --- layer 3: scalar aggregation + bias + sigmoid ---
    k_agg3<<<gN, BT, 0, stream>>>(t3, row_ptr, edges, dinv, b3, out, N);
}

// Round 9
// 310.633 us; speedup vs baseline: 2.7168x; 1.0819x over previous
//
#include <hip/hip_runtime.h>
#include <hip/hip_fp16.h>
#include <math.h>

#define NN 100000
#define NE 1600000
#define D 64
#define BSH 8                         // bin = dst >> 8  (256 nodes/bin)
#define NBIN 391                      // ceil(100000/256)
#define EB 8192                       // edges per binning block
#define NBB ((NE + EB - 1) / EB)      // 196
#define RPW 16                        // gemm rows per wave

typedef _Float16 h2 __attribute__((ext_vector_type(2)));

__device__ __forceinline__ float fdot2f(h2 a, h2 b, float c) {
#if defined(__has_builtin) && __has_builtin(__builtin_amdgcn_fdot2)
    return __builtin_amdgcn_fdot2(a, b, c, false);
#else
    return c + (float)a[0] * (float)b[0] + (float)a[1] * (float)b[1];
#endif
}

__device__ __forceinline__ unsigned packh2(float x, float y) {
    __half2 hh = __floats2half2_rn(x, y);
    return *(unsigned*)&hh;
}

// ---------------- pass A: per-block bin histogram (LDS atomics only) ----------------
__global__ void k_binhist(const int* __restrict__ dst, int* __restrict__ counts, int E) {
    __shared__ int h[NBIN];
    for (int i = threadIdx.x; i < NBIN; i += blockDim.x) h[i] = 0;
    __syncthreads();
    int e0 = blockIdx.x * EB;
    int e1 = min(e0 + EB, E);
    for (int e = e0 + threadIdx.x; e < e1; e += blockDim.x)
        atomicAdd(&h[dst[e] >> BSH], 1);
    __syncthreads();
    for (int i = threadIdx.x; i < NBIN; i += blockDim.x)
        counts[blockIdx.x * NBIN + i] = h[i];
}

// ---------------- scan: per-bin prefix over blocks + bin bases ----------------
__global__ void k_binscan(int* __restrict__ counts, int* __restrict__ binStart) {
    __shared__ int tot[512];
    int b = threadIdx.x;
    int sum = 0;
    if (b < NBIN) {
#pragma unroll 8
        for (int k = 0; k < NBB; k++) {
            int idx = k * NBIN + b;           // coalesced across b
            int c = counts[idx];
            counts[idx] = sum;                // exclusive per-block prefix
            sum += c;
        }
    }
    tot[b] = (b < NBIN) ? sum : 0;
    __syncthreads();
    int v = tot[b];
    for (int off = 1; off < 512; off <<= 1) {
        int add = (b >= off) ? tot[b - off] : 0;
        __syncthreads();
        tot[b] += add;
        __syncthreads();
    }
    if (b < NBIN) binStart[b] = tot[b] - v;   // exclusive bin base
    if (b == NBIN - 1) binStart[NBIN] = tot[b];  // == E
}

// ---------------- pass B: scatter edges into bin-contiguous order ----------------
__global__ void k_binscatter(const int* __restrict__ src, const int* __restrict__ dst,
                             const float* __restrict__ w, const int* __restrict__ counts,
                             const int* __restrict__ binStart, int2* __restrict__ binned,
                             int E) {
    __shared__ int cur[NBIN];
    for (int i = threadIdx.x; i < NBIN; i += blockDim.x)
        cur[i] = binStart[i] + counts[blockIdx.x * NBIN + i];
    __syncthreads();
    int e0 = blockIdx.x * EB;
    int e1 = min(e0 + EB, E);
    for (int e = e0 + threadIdx.x; e < e1; e += blockDim.x) {
        int d = dst[e];
        int pos = atomicAdd(&cur[d >> BSH], 1);
        binned[pos] = make_int2(((d & 255) << 17) | src[e], __float_as_int(w[e]));
    }
}

// ---------------- C1: per-bin deg/dinv + final row_ptr (LDS only) ----------------
__global__ void k_deg(const int2* __restrict__ binned, const int* __restrict__ binStart,
                      float* __restrict__ dinv, int* __restrict__ row_ptr, int n) {
    __shared__ int   cnt[256];
    __shared__ float ws[256];
    __shared__ int   off[256];
    int b = blockIdx.x, t = threadIdx.x;
    cnt[t] = 0; ws[t] = 0.0f;
    __syncthreads();
    int e0 = binStart[b], e1 = binStart[b + 1];
    for (int e = e0 + t; e < e1; e += 256) {
        int2 r = binned[e];
        int dlow = (unsigned)r.x >> 17;
        atomicAdd(&cnt[dlow], 1);
        atomicAdd(&ws[dlow], __int_as_float(r.y));
    }
    __syncthreads();
    int v = cnt[t];
    off[t] = v;
    __syncthreads();
    for (int o = 1; o < 256; o <<= 1) {
        int add = (t >= o) ? off[t - o] : 0;
        __syncthreads();
        off[t] += add;
        __syncthreads();
    }
    int node = b * 256 + t;
    if (node < n) {
        dinv[node] = rsqrtf(1.0f + ws[t]);       // self-loop weight 1
        row_ptr[node] = e0 + off[t] - v;          // exclusive
    }
    if (b == NBIN - 1 && t == 0) row_ptr[n] = binStart[NBIN];
}

// ---------------- C2: per-bin rank + fused norm -> compact CSR ----------------
__global__ void k_csr(const int2* __restrict__ binned, const int* __restrict__ binStart,
                      const int* __restrict__ row_ptr, const float* __restrict__ dinv,
                      int2* __restrict__ edges, int n) {
    __shared__ int   rp[256];
    __shared__ int   cur[256];
    __shared__ float dd[256];
    int b = blockIdx.x, t = threadIdx.x;
    int node = b * 256 + t;
    rp[t]  = (node < n) ? row_ptr[node] : 0;
    dd[t]  = (node < n) ? dinv[node] : 0.0f;
    cur[t] = 0;
    __syncthreads();
    int e0 = binStart[b], e1 = binStart[b + 1];
    for (int e = e0 + t; e < e1; e += 256) {
        int2 r = binned[e];
        int dlow = (unsigned)r.x >> 17;
        int s = r.x & 0x1FFFF;
        int rank = atomicAdd(&cur[dlow], 1);
        float nv = dinv[s] * __int_as_float(r.y) * dd[dlow];
        edges[rp[dlow] + rank] = make_int2(s, __float_as_int(nv));
    }
}

// ---------------- dense: T2 = X @ W (half-wave per row, lane owns column pair) ----------
// wc0/wc1: per-lane fp16 k-pair weights for cols 2c, 2c+1. Inner loop: 1 shfl + 2 fdot2.
template <int IN_HALF>
__global__ void k_gemm(const void* __restrict__ Xv, const float* __restrict__ W,
                       __half2* __restrict__ T2, int n) {
    int wid = (int)((blockIdx.x * blockDim.x + threadIdx.x) >> 6);
    int lane = threadIdx.x & 63;
    int c = lane & 31;
    int h = lane >> 5;
    int r0 = wid * RPW;
    if (r0 >= n) return;
    h2 wc0[32], wc1[32];
#pragma unroll
    for (int k2 = 0; k2 < 32; k2++) {
        float2 wa = ((const float2*)(W + (size_t)(2 * k2) * D))[c];      // W[2k2][2c,2c+1]
        float2 wb = ((const float2*)(W + (size_t)(2 * k2 + 1) * D))[c];  // W[2k2+1][2c,2c+1]
        h2 u, v;
        u[0] = (_Float16)wa.x; u[1] = (_Float16)wb.x;   // col 2c, k-pair
        v[0] = (_Float16)wa.y; v[1] = (_Float16)wb.y;   // col 2c+1, k-pair
        wc0[k2] = u; wc1[k2] = v;
    }
#pragma unroll
    for (int rr = 0; rr < RPW; rr += 2) {
        int r = r0 + rr + h;
        unsigned xh = 0;
        if (r < n) {
            if (IN_HALF) {
                xh = ((const unsigned*)Xv)[(size_t)r * 32 + c];
            } else {
                float2 xf = ((const float2*)Xv)[(size_t)r * 32 + c];
                xh = packh2(xf.x, xf.y);
            }
        }
        float acc0 = 0.0f, acc1 = 0.0f;
#pragma unroll
        for (int k2 = 0; k2 < 32; k2++) {
            int bb = __shfl((int)xh, h * 32 + k2);     // broadcast X[r][2k2,2k2+1]
            h2 xp = *(h2*)&bb;
            acc0 = fdot2f(xp, wc0[k2], acc0);
            acc1 = fdot2f(xp, wc1[k2], acc1);
        }
        if (r < n) T2[(size_t)r * 32 + c] = __floats2half2_rn(acc0, acc1);
    }
}

// ---------------- aggregation on fp16 rows: out = relu(A*T + b) ; optional fused @W3 ----
// Tiers 16/8/4/2 edges (ILP 8/4/2/1 per half-wave) + odd tail.
template <int FUSE_W3>
__global__ void k_agg(const __half2* __restrict__ T2, const int* __restrict__ row_ptr,
                      const int2* __restrict__ edges, const float* __restrict__ dinv,
                      const float* __restrict__ bias, const float* __restrict__ W3,
                      void* __restrict__ outv, int n) {
    int wave = (int)((blockIdx.x * blockDim.x + threadIdx.x) >> 6);
    int lane = threadIdx.x & 63;
    if (wave >= n) return;
    int c = lane & 31;
    int h = lane >> 5;
    int beg = row_ptr[wave], end = row_ptr[wave + 1];
    float ax = 0.0f, ay = 0.0f, bx = 0.0f, by = 0.0f;
    int i = beg;
    for (; i + 16 <= end; i += 16) {
        int2 er[8];
#pragma unroll
        for (int j = 0; j < 8; j++) er[j] = edges[i + 2 * j + h];
        __half2 tv[8];
#pragma unroll
        for (int j = 0; j < 8; j++) tv[j] = T2[(size_t)er[j].x * 32 + c];
#pragma unroll
        for (int j = 0; j < 8; j++) {
            float nv = __int_as_float(er[j].y);
            float2 f = __half22float2(tv[j]);
            if (j & 1) { bx += nv * f.x; by += nv * f.y; }
            else       { ax += nv * f.x; ay += nv * f.y; }
        }
    }
    if (i + 8 <= end) {
        int2 er[4];
#pragma unroll
        for (int j = 0; j < 4; j++) er[j] = edges[i + 2 * j + h];
        __half2 tv[4];
#pragma unroll
        for (int j = 0; j < 4; j++) tv[j] = T2[(size_t)er[j].x * 32 + c];
#pragma unroll
        for (int j = 0; j < 4; j++) {
            float nv = __int_as_float(er[j].y);
            float2 f = __half22float2(tv[j]);
            if (j & 1) { bx += nv * f.x; by += nv * f.y; }
            else       { ax += nv * f.x; ay += nv * f.y; }
        }
        i += 8;
    }
    if (i + 4 <= end) {
        int2 er[2];
#pragma unroll
        for (int j = 0; j < 2; j++) er[j] = edges[i + 2 * j + h];
#pragma unroll
        for (int j = 0; j < 2; j++) {
            float nv = __int_as_float(er[j].y);
            float2 f = __half22float2(T2[(size_t)er[j].x * 32 + c]);
            if (j & 1) { bx += nv * f.x; by += nv * f.y; }
            else       { ax += nv * f.x; ay += nv * f.y; }
        }
        i += 4;
    }
    if (i + 2 <= end) {
        int2 e = edges[i + h];
        float nv = __int_as_float(e.y);
        float2 f = __half22float2(T2[(size_t)e.x * 32 + c]);
        ax += nv * f.x; ay += nv * f.y;
        i += 2;
    }
    if (i < end && h == 0) {                       // odd leftover: half 0 only
        int2 e = edges[i];
        float nv = __int_as_float(e.y);
        float2 f = __half22float2(T2[(size_t)e.x * 32 + c]);
        ax += nv * f.x; ay += nv * f.y;
    }
    ax += bx; ay += by;
    ax += __shfl_xor(ax, 32);                      // combine halves
    ay += __shfl_xor(ay, 32);
    float dv = dinv[wave];
    float2 self = __half22float2(T2[(size_t)wave * 32 + c]);
    float hx = fmaxf(ax + dv * dv * self.x + bias[2 * c], 0.0f);
    float hy = fmaxf(ay + dv * dv * self.y + bias[2 * c + 1], 0.0f);
    if (FUSE_W3) {
        float pp = hx * W3[2 * c] + hy * W3[2 * c + 1];
#pragma unroll
        for (int off = 16; off; off >>= 1) pp += __shfl_xor(pp, off);
        if (lane == 0) ((float*)outv)[wave] = pp;
    } else {
        if (lane < 32) ((__half2*)outv)[(size_t)wave * 32 + c] = __floats2half2_rn(hx, hy);
    }
}

// ---------------- layer 3: scalar aggregation + sigmoid (8-way ILP, fp32) ----------------
__global__ void k_agg3(const float* __restrict__ t3, const int* __restrict__ row_ptr,
                       const int2* __restrict__ edges, const float* __restrict__ dinv,
                       const float* __restrict__ b3, float* __restrict__ out, int n) {
    int v = blockIdx.x * blockDim.x + threadIdx.x;
    if (v >= n) return;
    float dv = dinv[v];
    float acc0 = dv * dv * t3[v];
    float acc1 = 0.0f;
    int beg = row_ptr[v], end = row_ptr[v + 1];
    int i = beg;
    for (; i + 8 <= end; i += 8) {
        int2 er[8]; float av[8];
#pragma unroll
        for (int j = 0; j < 8; j++) er[j] = edges[i + j];
#pragma unroll
        for (int j = 0; j < 8; j++) av[j] = t3[er[j].x];
#pragma unroll
        for (int j = 0; j < 8; j++) {
            if (j & 1) acc1 += __int_as_float(er[j].y) * av[j];
            else       acc0 += __int_as_float(er[j].y) * av[j];
        }
    }
    for (; i < end; i++) {
        int2 e = edges[i];
        acc0 += __int_as_float(e.y) * t3[e.x];
    }
    float z = acc0 + acc1 + b3[0];
    out[v] = 1.0f / (1.0f + expf(-z));
}

extern "C" void kernel_launch(void* const* d_in, const int* in_sizes, int n_in,
                              void* d_out, int out_size, void* d_ws, size_t ws_size,
                              hipStream_t stream) {
    const float* x  = (const float*)d_in[0];
    const int*   ei = (const int*)d_in[1];
    const float* w  = (const float*)d_in[2];
    const float* W1 = (const float*)d_in[3];
    const float* b1 = (const float*)d_in[4];
    const float* W2 = (const float*)d_in[5];
    const float* b2 = (const float*)d_in[6];
    const float* W3 = (const float*)d_in[7];
    const float* b3 = (const float*)d_in[8];
    float* out = (float*)d_out;

    const int N = NN, E = NE;
    const int* src = ei;
    const int* dst = ei + E;

    // workspace carve (256B aligned)
    char* p = (char*)d_ws;
    auto alloc = [&](size_t bytes) -> char* {
        char* r = p;
        p += (bytes + 255) & ~(size_t)255;
        return r;
    };
    float* dinv    = (float*)alloc((size_t)N * 4);
    int*   row_ptr = (int*)alloc((size_t)(N + 1) * 4);
    int*   binStart= (int*)alloc((NBIN + 1) * 4);
    int*   counts  = (int*)alloc((size_t)NBB * NBIN * 4);
    int2*  binned  = (int2*)alloc((size_t)E * 8);       // bin-ordered records
    int2*  edges   = (int2*)alloc((size_t)E * 8);       // compact CSR (src, norm)
    __half2* bufA  = (__half2*)alloc((size_t)N * 32 * 4);
    __half2* bufB  = (__half2*)alloc((size_t)N * 32 * 4);
    float* t3      = (float*)alloc((size_t)N * 4);

    const int BT = 256;
    int gN = (N + BT - 1) / BT;
    int gW = (N * 64 + BT - 1) / BT;          // wave-per-node grids (4 waves/block)
    int gG = (N + RPW * 4 - 1) / (RPW * 4);   // gemm: 4 waves/block * RPW rows/wave

    // --- CSR build: zero global atomics ---
    k_binhist<<<NBB, BT, 0, stream>>>(dst, counts, E);
    k_binscan<<<1, 512, 0, stream>>>(counts, binStart);
    k_binscatter<<<NBB, BT, 0, stream>>>(src, dst, w, counts, binStart, binned, E);
    k_deg<<<NBIN, BT, 0, stream>>>(binned, binStart, dinv, row_ptr, N);
    k_csr<<<NBIN, BT, 0, stream>>>(binned, binStart, row_ptr, dinv, edges, N);

    // --- layer 1 ---
    k_gemm<0><<<gG, BT, 0, stream>>>(x, W1, bufA, N);
    k_agg<0><<<gW, BT, 0, stream>>>(bufA, row_ptr, edges, dinv, b1, nullptr, bufB, N);
    // --- layer 2 (fused h2 @ W3 epilogue -> t3) ---
    k_gemm<1><<<gG, BT, 0, stream>>>(bufB, W2, bufA, N);
    k_agg<1><<<gW, BT, 0, stream>>>(bufA, row_ptr, edges, dinv, b2, W3, t3, N);
    // --- layer 3: scalar aggregation + bias + sigmoid ---
    k_agg3<<<gN, BT, 0, stream>>>(t3, row_ptr, edges, dinv, b3, out, N);
}

// Round 10
// 226.298 us; speedup vs baseline: 3.7293x; 1.3727x over previous
//
#include <hip/hip_runtime.h>
#include <hip/hip_fp16.h>
#include <math.h>

#define NN 100000
#define NE 1600000
#define D 64
#define BSH 8                         // bin = dst >> 8  (256 nodes/bin)
#define NBIN 391                      // ceil(100000/256)
#define EB 8192                       // edges per binning block
#define NBB ((NE + EB - 1) / EB)      // 196

typedef _Float16 f16x8 __attribute__((ext_vector_type(8)));
typedef float f32x4 __attribute__((ext_vector_type(4)));

// ---------------- pass A: per-block bin histogram (LDS atomics only) ----------------
__global__ void k_binhist(const int* __restrict__ dst, int* __restrict__ counts, int E) {
    __shared__ int h[NBIN];
    for (int i = threadIdx.x; i < NBIN; i += blockDim.x) h[i] = 0;
    __syncthreads();
    int e0 = blockIdx.x * EB;
    int e1 = min(e0 + EB, E);
    for (int e = e0 + threadIdx.x; e < e1; e += blockDim.x)
        atomicAdd(&h[dst[e] >> BSH], 1);
    __syncthreads();
    for (int i = threadIdx.x; i < NBIN; i += blockDim.x)
        counts[blockIdx.x * NBIN + i] = h[i];
}

// ---------------- scan: per-bin prefix over blocks + bin bases ----------------
__global__ void k_binscan(int* __restrict__ counts, int* __restrict__ binStart) {
    __shared__ int tot[512];
    int b = threadIdx.x;
    int sum = 0;
    if (b < NBIN) {
#pragma unroll 8
        for (int k = 0; k < NBB; k++) {
            int idx = k * NBIN + b;           // coalesced across b
            int c = counts[idx];
            counts[idx] = sum;                // exclusive per-block prefix
            sum += c;
        }
    }
    tot[b] = (b < NBIN) ? sum : 0;
    __syncthreads();
    int v = tot[b];
    for (int off = 1; off < 512; off <<= 1) {
        int add = (b >= off) ? tot[b - off] : 0;
        __syncthreads();
        tot[b] += add;
        __syncthreads();
    }
    if (b < NBIN) binStart[b] = tot[b] - v;   // exclusive bin base
    if (b == NBIN - 1) binStart[NBIN] = tot[b];  // == E
}

// ---------------- pass B: scatter edges into bin-contiguous order ----------------
__global__ void k_binscatter(const int* __restrict__ src, const int* __restrict__ dst,
                             const float* __restrict__ w, const int* __restrict__ counts,
                             const int* __restrict__ binStart, int2* __restrict__ binned,
                             int E) {
    __shared__ int cur[NBIN];
    for (int i = threadIdx.x; i < NBIN; i += blockDim.x)
        cur[i] = binStart[i] + counts[blockIdx.x * NBIN + i];
    __syncthreads();
    int e0 = blockIdx.x * EB;
    int e1 = min(e0 + EB, E);
    for (int e = e0 + threadIdx.x; e < e1; e += blockDim.x) {
        int d = dst[e];
        int pos = atomicAdd(&cur[d >> BSH], 1);
        binned[pos] = make_int2(((d & 255) << 17) | src[e], __float_as_int(w[e]));
    }
}

// ---------------- C1: per-bin deg/dinv + final row_ptr (LDS only) ----------------
__global__ void k_deg(const int2* __restrict__ binned, const int* __restrict__ binStart,
                      float* __restrict__ dinv, int* __restrict__ row_ptr, int n) {
    __shared__ int   cnt[256];
    __shared__ float ws[256];
    __shared__ int   off[256];
    int b = blockIdx.x, t = threadIdx.x;
    cnt[t] = 0; ws[t] = 0.0f;
    __syncthreads();
    int e0 = binStart[b], e1 = binStart[b + 1];
    for (int e = e0 + t; e < e1; e += 256) {
        int2 r = binned[e];
        int dlow = (unsigned)r.x >> 17;
        atomicAdd(&cnt[dlow], 1);
        atomicAdd(&ws[dlow], __int_as_float(r.y));
    }
    __syncthreads();
    int v = cnt[t];
    off[t] = v;
    __syncthreads();
    for (int o = 1; o < 256; o <<= 1) {
        int add = (t >= o) ? off[t - o] : 0;
        __syncthreads();
        off[t] += add;
        __syncthreads();
    }
    int node = b * 256 + t;
    if (node < n) {
        dinv[node] = rsqrtf(1.0f + ws[t]);       // self-loop weight 1
        row_ptr[node] = e0 + off[t] - v;          // exclusive
    }
    if (b == NBIN - 1 && t == 0) row_ptr[n] = binStart[NBIN];
}

// ---------------- C2: per-bin rank + fused norm -> compact CSR ----------------
__global__ void k_csr(const int2* __restrict__ binned, const int* __restrict__ binStart,
                      const int* __restrict__ row_ptr, const float* __restrict__ dinv,
                      int2* __restrict__ edges, int n) {
    __shared__ int   rp[256];
    __shared__ int   cur[256];
    __shared__ float dd[256];
    int b = blockIdx.x, t = threadIdx.x;
    int node = b * 256 + t;
    rp[t]  = (node < n) ? row_ptr[node] : 0;
    dd[t]  = (node < n) ? dinv[node] : 0.0f;
    cur[t] = 0;
    __syncthreads();
    int e0 = binStart[b], e1 = binStart[b + 1];
    for (int e = e0 + t; e < e1; e += 256) {
        int2 r = binned[e];
        int dlow = (unsigned)r.x >> 17;
        int s = r.x & 0x1FFFF;
        int rank = atomicAdd(&cur[dlow], 1);
        float nv = dinv[s] * __int_as_float(r.y) * dd[dlow];
        edges[rp[dlow] + rank] = make_int2(s, __float_as_int(nv));
    }
}

// ---------------- dense: T = X @ W via MFMA 16x16x32 f16 ----------------
// Wave computes 32 rows (2 tiles of 16). A/B frag: lane&15 = row/col,
// 8 contiguous k at (lane>>4)*8. C/D: col=lane&15, row=(lane>>4)*4+reg.
template <int IN_HALF>
__global__ void k_gemm(const void* __restrict__ Xv, const float* __restrict__ W,
                       __half* __restrict__ T, int n) {
    int wid = (int)((blockIdx.x * blockDim.x + threadIdx.x) >> 6);
    int lane = threadIdx.x & 63;
    int col16 = lane & 15, kg = lane >> 4;
    int r0 = wid * 32;
    if (r0 >= n) return;
    // B fragments: bf[kk][ct], elem j = W[kk*32 + kg*8 + j][ct*16 + col16]
    f16x8 bf[2][4];
#pragma unroll
    for (int kk = 0; kk < 2; kk++)
#pragma unroll
        for (int ct = 0; ct < 4; ct++) {
            f16x8 b;
#pragma unroll
            for (int j = 0; j < 8; j++)
                b[j] = (_Float16)W[(size_t)(kk * 32 + kg * 8 + j) * D + ct * 16 + col16];
            bf[kk][ct] = b;
        }
#pragma unroll
    for (int tt = 0; tt < 2; tt++) {
        int row = r0 + tt * 16 + col16;           // this lane's A row
        f16x8 a0, a1;
        if (IN_HALF) {
            const _Float16* xr = (const _Float16*)Xv + (size_t)row * D;
            a0 = *(const f16x8*)(xr + kg * 8);
            a1 = *(const f16x8*)(xr + 32 + kg * 8);
        } else {
            const float* xr = (const float*)Xv + (size_t)row * D;
#pragma unroll
            for (int j = 0; j < 8; j++) {
                a0[j] = (_Float16)xr[kg * 8 + j];
                a1[j] = (_Float16)xr[32 + kg * 8 + j];
            }
        }
#pragma unroll
        for (int ct = 0; ct < 4; ct++) {
            f32x4 z = {0.0f, 0.0f, 0.0f, 0.0f};
            z = __builtin_amdgcn_mfma_f32_16x16x32_f16(a0, bf[0][ct], z, 0, 0, 0);
            z = __builtin_amdgcn_mfma_f32_16x16x32_f16(a1, bf[1][ct], z, 0, 0, 0);
            __half* to = T + (size_t)(r0 + tt * 16 + kg * 4) * D + ct * 16 + col16;
#pragma unroll
            for (int r = 0; r < 4; r++)
                to[(size_t)r * D] = __float2half(z[r]);
        }
    }
}

// ---------------- aggregation on fp16 rows: out = relu(A*T + b) ; optional fused @W3 ----
// Tiers 16/8/4/2 edges (ILP 8/4/2/1 per half-wave) + odd tail.
template <int FUSE_W3>
__global__ void k_agg(const __half2* __restrict__ T2, const int* __restrict__ row_ptr,
                      const int2* __restrict__ edges, const float* __restrict__ dinv,
                      const float* __restrict__ bias, const float* __restrict__ W3,
                      void* __restrict__ outv, int n) {
    int wave = (int)((blockIdx.x * blockDim.x + threadIdx.x) >> 6);
    int lane = threadIdx.x & 63;
    if (wave >= n) return;
    int c = lane & 31;
    int h = lane >> 5;
    int beg = row_ptr[wave], end = row_ptr[wave + 1];
    float ax = 0.0f, ay = 0.0f, bx = 0.0f, by = 0.0f;
    int i = beg;
    for (; i + 16 <= end; i += 16) {
        int2 er[8];
#pragma unroll
        for (int j = 0; j < 8; j++) er[j] = edges[i + 2 * j + h];
        __half2 tv[8];
#pragma unroll
        for (int j = 0; j < 8; j++) tv[j] = T2[(size_t)er[j].x * 32 + c];
#pragma unroll
        for (int j = 0; j < 8; j++) {
            float nv = __int_as_float(er[j].y);
            float2 f = __half22float2(tv[j]);
            if (j & 1) { bx += nv * f.x; by += nv * f.y; }
            else       { ax += nv * f.x; ay += nv * f.y; }
        }
    }
    if (i + 8 <= end) {
        int2 er[4];
#pragma unroll
        for (int j = 0; j < 4; j++) er[j] = edges[i + 2 * j + h];
        __half2 tv[4];
#pragma unroll
        for (int j = 0; j < 4; j++) tv[j] = T2[(size_t)er[j].x * 32 + c];
#pragma unroll
        for (int j = 0; j < 4; j++) {
            float nv = __int_as_float(er[j].y);
            float2 f = __half22float2(tv[j]);
            if (j & 1) { bx += nv * f.x; by += nv * f.y; }
            else       { ax += nv * f.x; ay += nv * f.y; }
        }
        i += 8;
    }
    if (i + 4 <= end) {
        int2 er[2];
#pragma unroll
        for (int j = 0; j < 2; j++) er[j] = edges[i + 2 * j + h];
#pragma unroll
        for (int j = 0; j < 2; j++) {
            float nv = __int_as_float(er[j].y);
            float2 f = __half22float2(T2[(size_t)er[j].x * 32 + c]);
            if (j & 1) { bx += nv * f.x; by += nv * f.y; }
            else       { ax += nv * f.x; ay += nv * f.y; }
        }
        i += 4;
    }
    if (i + 2 <= end) {
        int2 e = edges[i + h];
        float nv = __int_as_float(e.y);
        float2 f = __half22float2(T2[(size_t)e.x * 32 + c]);
        ax += nv * f.x; ay += nv * f.y;
        i += 2;
    }
    if (i < end && h == 0) {                       // odd leftover: half 0 only
        int2 e = edges[i];
        float nv = __int_as_float(e.y);
        float2 f = __half22float2(T2[(size_t)e.x * 32 + c]);
        ax += nv * f.x; ay += nv * f.y;
    }
    ax += bx; ay += by;
    ax += __shfl_xor(ax, 32);                      // combine halves
    ay += __shfl_xor(ay, 32);
    float dv = dinv[wave];
    float2 self = __half22float2(T2[(size_t)wave * 32 + c]);
    float hx = fmaxf(ax + dv * dv * self.x + bias[2 * c], 0.0f);
    float hy = fmaxf(ay + dv * dv * self.y + bias[2 * c + 1], 0.0f);
    if (FUSE_W3) {
        float pp = hx * W3[2 * c] + hy * W3[2 * c + 1];
#pragma unroll
        for (int off = 16; off; off >>= 1) pp += __shfl_xor(pp, off);
        if (lane == 0) ((float*)outv)[wave] = pp;
    } else {
        if (lane < 32) ((__half2*)outv)[(size_t)wave * 32 + c] = __floats2half2_rn(hx, hy);
    }
}

// ---------------- layer 3: scalar aggregation + sigmoid (8-way ILP, fp32) ----------------
__global__ void k_agg3(const float* __restrict__ t3, const int* __restrict__ row_ptr,
                       const int2* __restrict__ edges, const float* __restrict__ dinv,
                       const float* __restrict__ b3, float* __restrict__ out, int n) {
    int v = blockIdx.x * blockDim.x + threadIdx.x;
    if (v >= n) return;
    float dv = dinv[v];
    float acc0 = dv * dv * t3[v];
    float acc1 = 0.0f;
    int beg = row_ptr[v], end = row_ptr[v + 1];
    int i = beg;
    for (; i + 8 <= end; i += 8) {
        int2 er[8]; float av[8];
#pragma unroll
        for (int j = 0; j < 8; j++) er[j] = edges[i + j];
#pragma unroll
        for (int j = 0; j < 8; j++) av[j] = t3[er[j].x];
#pragma unroll
        for (int j = 0; j < 8; j++) {
            if (j & 1) acc1 += __int_as_float(er[j].y) * av[j];
            else       acc0 += __int_as_float(er[j].y) * av[j];
        }
    }
    for (; i < end; i++) {
        int2 e = edges[i];
        acc0 += __int_as_float(e.y) * t3[e.x];
    }
    float z = acc0 + acc1 + b3[0];
    out[v] = 1.0f / (1.0f + expf(-z));
}

extern "C" void kernel_launch(void* const* d_in, const int* in_sizes, int n_in,
                              void* d_out, int out_size, void* d_ws, size_t ws_size,
                              hipStream_t stream) {
    const float* x  = (const float*)d_in[0];
    const int*   ei = (const int*)d_in[1];
    const float* w  = (const float*)d_in[2];
    const float* W1 = (const float*)d_in[3];
    const float* b1 = (const float*)d_in[4];
    const float* W2 = (const float*)d_in[5];
    const float* b2 = (const float*)d_in[6];
    const float* W3 = (const float*)d_in[7];
    const float* b3 = (const float*)d_in[8];
    float* out = (float*)d_out;

    const int N = NN, E = NE;
    const int* src = ei;
    const int* dst = ei + E;

    // workspace carve (256B aligned)
    char* p = (char*)d_ws;
    auto alloc = [&](size_t bytes) -> char* {
        char* r = p;
        p += (bytes + 255) & ~(size_t)255;
        return r;
    };
    float* dinv    = (float*)alloc((size_t)N * 4);
    int*   row_ptr = (int*)alloc((size_t)(N + 1) * 4);
    int*   binStart= (int*)alloc((NBIN + 1) * 4);
    int*   counts  = (int*)alloc((size_t)NBB * NBIN * 4);
    int2*  binned  = (int2*)alloc((size_t)E * 8);       // bin-ordered records
    int2*  edges   = (int2*)alloc((size_t)E * 8);       // compact CSR (src, norm)
    __half* bufA   = (__half*)alloc((size_t)N * D * 2);
    __half* bufB   = (__half*)alloc((size_t)N * D * 2);
    float* t3      = (float*)alloc((size_t)N * 4);

    const int BT = 256;
    int gN = (N + BT - 1) / BT;
    int gW = (N * 64 + BT - 1) / BT;               // wave-per-node grids (4 waves/block)
    int nWaves = (N + 31) / 32;                    // gemm: wave per 32 rows
    int gG = (nWaves * 64 + BT - 1) / BT;

    // --- CSR build: zero global atomics ---
    k_binhist<<<NBB, BT, 0, stream>>>(dst, counts, E);
    k_binscan<<<1, 512, 0, stream>>>(counts, binStart);
    k_binscatter<<<NBB, BT, 0, stream>>>(src, dst, w, counts, binStart, binned, E);
    k_deg<<<NBIN, BT, 0, stream>>>(binned, binStart, dinv, row_ptr, N);
    k_csr<<<NBIN, BT, 0, stream>>>(binned, binStart, row_ptr, dinv, edges, N);

    // --- layer 1 ---
    k_gemm<0><<<gG, BT, 0, stream>>>(x, W1, bufA, N);
    k_agg<0><<<gW, BT, 0, stream>>>((const __half2*)bufA, row_ptr, edges, dinv, b1, nullptr, bufB, N);
    // --- layer 2 (fused h2 @ W3 epilogue -> t3) ---
    k_gemm<1><<<gG, BT, 0, stream>>>(bufB, W2, bufA, N);
    k_agg<1><<<gW, BT, 0, stream>>>((const __half2*)bufA, row_ptr, edges, dinv, b2, W3, t3, N);
    // --- layer 3: scalar aggregation + bias + sigmoid ---
    k_agg3<<<gN, BT, 0, stream>>>(t3, row_ptr, edges, dinv, b3, out, N);
}

// Round 11
// 223.740 us; speedup vs baseline: 3.7719x; 1.0114x over previous
//
#include <hip/hip_runtime.h>
#include <hip/hip_fp16.h>
#include <math.h>

#define NN 100000
#define NE 1600000
#define D 64
#define BSH 8                         // bin = dst >> 8  (256 nodes/bin)
#define NBIN 391                      // ceil(100000/256)
#define EB 8192                       // edges per binning block
#define NBB ((NE + EB - 1) / EB)      // 196

typedef _Float16 f16x8 __attribute__((ext_vector_type(8)));
typedef float f32x4 __attribute__((ext_vector_type(4)));

__device__ __forceinline__ int2 ldnt2(const int2* p) {
    unsigned long long r = __builtin_nontemporal_load((const unsigned long long*)p);
    int2 o;
    o.x = (int)(unsigned)(r & 0xffffffffu);
    o.y = (int)(unsigned)(r >> 32);
    return o;
}

// ---------------- pass A: per-block bin histogram (LDS atomics only) ----------------
__global__ void k_binhist(const int* __restrict__ dst, int* __restrict__ counts, int E) {
    __shared__ int h[NBIN];
    for (int i = threadIdx.x; i < NBIN; i += blockDim.x) h[i] = 0;
    __syncthreads();
    int e0 = blockIdx.x * EB;
    int e1 = min(e0 + EB, E);
    for (int e = e0 + threadIdx.x; e < e1; e += blockDim.x)
        atomicAdd(&h[__builtin_nontemporal_load(dst + e) >> BSH], 1);
    __syncthreads();
    for (int i = threadIdx.x; i < NBIN; i += blockDim.x)
        counts[blockIdx.x * NBIN + i] = h[i];
}

// ---------------- scan: per-bin prefix over blocks + bin bases ----------------
__global__ void k_binscan(int* __restrict__ counts, int* __restrict__ binStart) {
    __shared__ int tot[512];
    int b = threadIdx.x;
    int sum = 0;
    if (b < NBIN) {
#pragma unroll 8
        for (int k = 0; k < NBB; k++) {
            int idx = k * NBIN + b;           // coalesced across b
            int c = counts[idx];
            counts[idx] = sum;                // exclusive per-block prefix
            sum += c;
        }
    }
    tot[b] = (b < NBIN) ? sum : 0;
    __syncthreads();
    int v = tot[b];
    for (int off = 1; off < 512; off <<= 1) {
        int add = (b >= off) ? tot[b - off] : 0;
        __syncthreads();
        tot[b] += add;
        __syncthreads();
    }
    if (b < NBIN) binStart[b] = tot[b] - v;   // exclusive bin base
    if (b == NBIN - 1) binStart[NBIN] = tot[b];  // == E
}

// ---------------- pass B: scatter edges into bin-contiguous order ----------------
__global__ void k_binscatter(const int* __restrict__ src, const int* __restrict__ dst,
                             const float* __restrict__ w, const int* __restrict__ counts,
                             const int* __restrict__ binStart, int2* __restrict__ binned,
                             int E) {
    __shared__ int cur[NBIN];
    for (int i = threadIdx.x; i < NBIN; i += blockDim.x)
        cur[i] = binStart[i] + counts[blockIdx.x * NBIN + i];
    __syncthreads();
    int e0 = blockIdx.x * EB;
    int e1 = min(e0 + EB, E);
    for (int e = e0 + threadIdx.x; e < e1; e += blockDim.x) {
        int d = __builtin_nontemporal_load(dst + e);
        int s = __builtin_nontemporal_load(src + e);
        float wv = __builtin_nontemporal_load(w + e);
        int pos = atomicAdd(&cur[d >> BSH], 1);
        binned[pos] = make_int2(((d & 255) << 17) | s, __float_as_int(wv));
    }
}

// ---------------- fused deg + CSR: dinv/row_ptr (pass 1) + rank/write (pass 2) ------
// Edge value = w * dinv[dst] only (T rows are pre-scaled by dinv[src] in gemm).
__global__ void k_degcsr(const int2* __restrict__ binned, const int* __restrict__ binStart,
                         float* __restrict__ dinv, int* __restrict__ row_ptr,
                         int2* __restrict__ edges, int n) {
    __shared__ int   cnt[256];
    __shared__ float ws[256];
    __shared__ int   off[256];
    __shared__ int   rp[256];
    __shared__ float dd[256];
    int b = blockIdx.x, t = threadIdx.x;
    cnt[t] = 0; ws[t] = 0.0f;
    __syncthreads();
    int e0 = binStart[b], e1 = binStart[b + 1];
    for (int e = e0 + t; e < e1; e += 256) {
        int2 r = binned[e];
        int dlow = (unsigned)r.x >> 17;
        atomicAdd(&cnt[dlow], 1);
        atomicAdd(&ws[dlow], __int_as_float(r.y));
    }
    __syncthreads();
    int v = cnt[t];
    off[t] = v;
    __syncthreads();
    for (int o = 1; o < 256; o <<= 1) {
        int add = (t >= o) ? off[t - o] : 0;
        __syncthreads();
        off[t] += add;
        __syncthreads();
    }
    int node = b * 256 + t;
    float dvv = rsqrtf(1.0f + ws[t]);        // self-loop weight 1
    rp[t] = e0 + off[t] - v;                 // exclusive row base
    dd[t] = dvv;
    if (node < n) { dinv[node] = dvv; row_ptr[node] = rp[t]; }
    if (b == NBIN - 1 && t == 0) row_ptr[n] = binStart[NBIN];
    cnt[t] = 0;                              // reuse as rank cursor
    __syncthreads();
    for (int e = e0 + t; e < e1; e += 256) { // pass 2: bin is L2-hot
        int2 r = binned[e];
        int dlow = (unsigned)r.x >> 17;
        int s = r.x & 0x1FFFF;
        int rank = atomicAdd(&cnt[dlow], 1);
        float nv = __int_as_float(r.y) * dd[dlow];   // w * dinv[dst]
        edges[rp[dlow] + rank] = make_int2(s, __float_as_int(nv));
    }
}

// ---------------- dense: T' = dinv ⊙ (X @ W) via MFMA 16x16x32 f16 ----------------
// Wave computes 32 rows (2 tiles of 16). A/B frag: lane&15 = row/col,
// 8 contiguous k at (lane>>4)*8. C/D: col=lane&15, row=(lane>>4)*4+reg.
template <int IN_HALF>
__global__ void k_gemm(const void* __restrict__ Xv, const float* __restrict__ W,
                       const float* __restrict__ dinv, __half* __restrict__ T, int n) {
    int wid = (int)((blockIdx.x * blockDim.x + threadIdx.x) >> 6);
    int lane = threadIdx.x & 63;
    int col16 = lane & 15, kg = lane >> 4;
    int r0 = wid * 32;
    if (r0 >= n) return;
    // B fragments: bf[kk][ct], elem j = W[kk*32 + kg*8 + j][ct*16 + col16]
    f16x8 bf[2][4];
#pragma unroll
    for (int kk = 0; kk < 2; kk++)
#pragma unroll
        for (int ct = 0; ct < 4; ct++) {
            f16x8 b;
#pragma unroll
            for (int j = 0; j < 8; j++)
                b[j] = (_Float16)W[(size_t)(kk * 32 + kg * 8 + j) * D + ct * 16 + col16];
            bf[kk][ct] = b;
        }
#pragma unroll
    for (int tt = 0; tt < 2; tt++) {
        int row = r0 + tt * 16 + col16;           // this lane's A row
        f16x8 a0, a1;
        if (IN_HALF) {
            const _Float16* xr = (const _Float16*)Xv + (size_t)row * D;
            a0 = *(const f16x8*)(xr + kg * 8);
            a1 = *(const f16x8*)(xr + 32 + kg * 8);
        } else {
            const float* xr = (const float*)Xv + (size_t)row * D;
#pragma unroll
            for (int j = 0; j < 8; j++) {
                a0[j] = (_Float16)xr[kg * 8 + j];
                a1[j] = (_Float16)xr[32 + kg * 8 + j];
            }
        }
        float dvr[4];
#pragma unroll
        for (int r = 0; r < 4; r++) dvr[r] = dinv[r0 + tt * 16 + kg * 4 + r];
#pragma unroll
        for (int ct = 0; ct < 4; ct++) {
            f32x4 z = {0.0f, 0.0f, 0.0f, 0.0f};
            z = __builtin_amdgcn_mfma_f32_16x16x32_f16(a0, bf[0][ct], z, 0, 0, 0);
            z = __builtin_amdgcn_mfma_f32_16x16x32_f16(a1, bf[1][ct], z, 0, 0, 0);
            __half* to = T + (size_t)(r0 + tt * 16 + kg * 4) * D + ct * 16 + col16;
#pragma unroll
            for (int r = 0; r < 4; r++)
                to[(size_t)r * D] = __float2half(z[r] * dvr[r]);
        }
    }
}

// ---------------- aggregation on pre-scaled fp16 rows ----------------
// out = relu(Σ ev·T'[s] + dv·T'[v] + b); optional fused @W3 (writes dv·t3).
// Tiers 16/8/4/2 edges (ILP 8/4/2/1 per half-wave) + odd tail; NT edge loads.
template <int FUSE_W3>
__global__ void k_agg(const __half2* __restrict__ T2, const int* __restrict__ row_ptr,
                      const int2* __restrict__ edges, const float* __restrict__ dinv,
                      const float* __restrict__ bias, const float* __restrict__ W3,
                      void* __restrict__ outv, int n) {
    int wave = (int)((blockIdx.x * blockDim.x + threadIdx.x) >> 6);
    int lane = threadIdx.x & 63;
    if (wave >= n) return;
    int c = lane & 31;
    int h = lane >> 5;
    int beg = row_ptr[wave], end = row_ptr[wave + 1];
    float ax = 0.0f, ay = 0.0f, bx = 0.0f, by = 0.0f;
    int i = beg;
    for (; i + 16 <= end; i += 16) {
        int2 er[8];
#pragma unroll
        for (int j = 0; j < 8; j++) er[j] = ldnt2(&edges[i + 2 * j + h]);
        __half2 tv[8];
#pragma unroll
        for (int j = 0; j < 8; j++) tv[j] = T2[(size_t)er[j].x * 32 + c];
#pragma unroll
        for (int j = 0; j < 8; j++) {
            float nv = __int_as_float(er[j].y);
            float2 f = __half22float2(tv[j]);
            if (j & 1) { bx += nv * f.x; by += nv * f.y; }
            else       { ax += nv * f.x; ay += nv * f.y; }
        }
    }
    if (i + 8 <= end) {
        int2 er[4];
#pragma unroll
        for (int j = 0; j < 4; j++) er[j] = ldnt2(&edges[i + 2 * j + h]);
        __half2 tv[4];
#pragma unroll
        for (int j = 0; j < 4; j++) tv[j] = T2[(size_t)er[j].x * 32 + c];
#pragma unroll
        for (int j = 0; j < 4; j++) {
            float nv = __int_as_float(er[j].y);
            float2 f = __half22float2(tv[j]);
            if (j & 1) { bx += nv * f.x; by += nv * f.y; }
            else       { ax += nv * f.x; ay += nv * f.y; }
        }
        i += 8;
    }
    if (i + 4 <= end) {
        int2 er[2];
#pragma unroll
        for (int j = 0; j < 2; j++) er[j] = ldnt2(&edges[i + 2 * j + h]);
#pragma unroll
        for (int j = 0; j < 2; j++) {
            float nv = __int_as_float(er[j].y);
            float2 f = __half22float2(T2[(size_t)er[j].x * 32 + c]);
            if (j & 1) { bx += nv * f.x; by += nv * f.y; }
            else       { ax += nv * f.x; ay += nv * f.y; }
        }
        i += 4;
    }
    if (i + 2 <= end) {
        int2 e = ldnt2(&edges[i + h]);
        float nv = __int_as_float(e.y);
        float2 f = __half22float2(T2[(size_t)e.x * 32 + c]);
        ax += nv * f.x; ay += nv * f.y;
        i += 2;
    }
    if (i < end && h == 0) {                       // odd leftover: half 0 only
        int2 e = ldnt2(&edges[i]);
        float nv = __int_as_float(e.y);
        float2 f = __half22float2(T2[(size_t)e.x * 32 + c]);
        ax += nv * f.x; ay += nv * f.y;
    }
    ax += bx; ay += by;
    ax += __shfl_xor(ax, 32);                      // combine halves
    ay += __shfl_xor(ay, 32);
    float dv = dinv[wave];
    float2 self = __half22float2(T2[(size_t)wave * 32 + c]);  // pre-scaled by dinv[v]
    float hx = fmaxf(ax + dv * self.x + bias[2 * c], 0.0f);
    float hy = fmaxf(ay + dv * self.y + bias[2 * c + 1], 0.0f);
    if (FUSE_W3) {
        float pp = hx * W3[2 * c] + hy * W3[2 * c + 1];
#pragma unroll
        for (int off = 16; off; off >>= 1) pp += __shfl_xor(pp, off);
        if (lane == 0) ((float*)outv)[wave] = dv * pp;   // store pre-scaled t3'
    } else {
        if (lane < 32) ((__half2*)outv)[(size_t)wave * 32 + c] = __floats2half2_rn(hx, hy);
    }
}

// ---------------- layer 3 on pre-scaled t3': sigmoid(Σ ev·t3'[s] + dv·t3'[v] + b3) ----
__global__ void k_agg3(const float* __restrict__ t3, const int* __restrict__ row_ptr,
                       const int2* __restrict__ edges, const float* __restrict__ dinv,
                       const float* __restrict__ b3, float* __restrict__ out, int n) {
    int v = blockIdx.x * blockDim.x + threadIdx.x;
    if (v >= n) return;
    float dv = dinv[v];
    float acc0 = dv * t3[v];
    float acc1 = 0.0f;
    int beg = row_ptr[v], end = row_ptr[v + 1];
    int i = beg;
    for (; i + 8 <= end; i += 8) {
        int2 er[8]; float av[8];
#pragma unroll
        for (int j = 0; j < 8; j++) er[j] = ldnt2(&edges[i + j]);
#pragma unroll
        for (int j = 0; j < 8; j++) av[j] = t3[er[j].x];
#pragma unroll
        for (int j = 0; j < 8; j++) {
            if (j & 1) acc1 += __int_as_float(er[j].y) * av[j];
            else       acc0 += __int_as_float(er[j].y) * av[j];
        }
    }
    for (; i < end; i++) {
        int2 e = ldnt2(&edges[i]);
        acc0 += __int_as_float(e.y) * t3[e.x];
    }
    float z = acc0 + acc1 + b3[0];
    out[v] = 1.0f / (1.0f + expf(-z));
}

extern "C" void kernel_launch(void* const* d_in, const int* in_sizes, int n_in,
                              void* d_out, int out_size, void* d_ws, size_t ws_size,
                              hipStream_t stream) {
    const float* x  = (const float*)d_in[0];
    const int*   ei = (const int*)d_in[1];
    const float* w  = (const float*)d_in[2];
    const float* W1 = (const float*)d_in[3];
    const float* b1 = (const float*)d_in[4];
    const float* W2 = (const float*)d_in[5];
    const float* b2 = (const float*)d_in[6];
    const float* W3 = (const float*)d_in[7];
    const float* b3 = (const float*)d_in[8];
    float* out = (float*)d_out;

    const int N = NN, E = NE;
    const int* src = ei;
    const int* dst = ei + E;

    // workspace carve (256B aligned)
    char* p = (char*)d_ws;
    auto alloc = [&](size_t bytes) -> char* {
        char* r = p;
        p += (bytes + 255) & ~(size_t)255;
        return r;
    };
    float* dinv    = (float*)alloc((size_t)N * 4);
    int*   row_ptr = (int*)alloc((size_t)(N + 1) * 4);
    int*   binStart= (int*)alloc((NBIN + 1) * 4);
    int*   counts  = (int*)alloc((size_t)NBB * NBIN * 4);
    int2*  binned  = (int2*)alloc((size_t)E * 8);       // bin-ordered records
    int2*  edges   = (int2*)alloc((size_t)E * 8);       // compact CSR (src, w*dinv[dst])
    __half* bufA   = (__half*)alloc((size_t)N * D * 2);
    __half* bufB   = (__half*)alloc((size_t)N * D * 2);
    float* t3      = (float*)alloc((size_t)N * 4);

    const int BT = 256;
    int gN = (N + BT - 1) / BT;
    int gW = (N * 64 + BT - 1) / BT;               // wave-per-node grids (4 waves/block)
    int nWaves = (N + 31) / 32;                    // gemm: wave per 32 rows
    int gG = (nWaves * 64 + BT - 1) / BT;

    // --- CSR build: zero global atomics ---
    k_binhist<<<NBB, BT, 0, stream>>>(dst, counts, E);
    k_binscan<<<1, 512, 0, stream>>>(counts, binStart);
    k_binscatter<<<NBB, BT, 0, stream>>>(src, dst, w, counts, binStart, binned, E);
    k_degcsr<<<NBIN, BT, 0, stream>>>(binned, binStart, dinv, row_ptr, edges, N);

    // --- layer 1 ---
    k_gemm<0><<<gG, BT, 0, stream>>>(x, W1, dinv, bufA, N);
    k_agg<0><<<gW, BT, 0, stream>>>((const __half2*)bufA, row_ptr, edges, dinv, b1, nullptr, bufB, N);
    // --- layer 2 (fused h2 @ W3 epilogue -> t3') ---
    k_gemm<1><<<gG, BT, 0, stream>>>(bufB, W2, dinv, bufA, N);
    k_agg<1><<<gW, BT, 0, stream>>>((const __half2*)bufA, row_ptr, edges, dinv, b2, W3, t3, N);
    // --- layer 3: scalar aggregation + bias + sigmoid ---
    k_agg3<<<gN, BT, 0, stream>>>(t3, row_ptr, edges, dinv, b3, out, N);
}